// Round 1
// baseline (2818.762 us; speedup 1.0000x reference)
//
#include <hip/hip_runtime.h>
#include <math.h>

#define NGRAPH 256
#define NPG 64
#define NFEAT 64
#define HC 504
#define NLAY 4
#define EPER 1024
#define NTRIU 2016
#define DCAT 4032
#define HID1 1024
#define HID2 512

// ---------------------------------------------------------------------------
// Build per-graph normalized adjacency, stored TRANSPOSED: AT[g][src][dst]
// AT[s][d] += dinv[s]*dinv[d] per edge; AT[n][n] += dinv[n]^2 (self loop term)
// ---------------------------------------------------------------------------
__global__ __launch_bounds__(256) void build_adj(const int* __restrict__ esrc,
                                                 const int* __restrict__ edst,
                                                 float* __restrict__ AT)
{
    int g = blockIdx.x;
    __shared__ float A[4096];
    __shared__ int   cnt[64];
    __shared__ float dinv[64];
    int tid = threadIdx.x;
    for (int i = tid; i < 4096; i += 256) A[i] = 0.f;
    if (tid < 64) cnt[tid] = 0;
    __syncthreads();
    for (int e = tid; e < EPER; e += 256)
        atomicAdd(&cnt[edst[(size_t)g * EPER + e] & 63], 1);
    __syncthreads();
    if (tid < 64) dinv[tid] = rsqrtf((float)cnt[tid] + 1.0f);
    __syncthreads();
    for (int e = tid; e < EPER; e += 256) {
        int s = esrc[(size_t)g * EPER + e] & 63;
        int d = edst[(size_t)g * EPER + e] & 63;
        atomicAdd(&A[s * 64 + d], dinv[s] * dinv[d]);   // transposed store
    }
    __syncthreads();
    if (tid < 64) A[tid * 64 + tid] += dinv[tid] * dinv[tid];
    __syncthreads();
    for (int i = tid; i < 4096; i += 256) AT[(size_t)g * 4096 + i] = A[i];
}

// ---------------------------------------------------------------------------
// triu(64, k=1) index tables
// ---------------------------------------------------------------------------
__global__ void triu_idx(int* __restrict__ iu, int* __restrict__ ju)
{
    int i = threadIdx.x;
    if (i >= 63) return;
    int off = 63 * i - i * (i - 1) / 2;
    for (int j = i + 1; j < 64; ++j) { iu[off] = i; ju[off] = j; ++off; }
}

// ---------------------------------------------------------------------------
// Generic fp32 SGEMM: C[M,N] = A[M,K] @ B[K,N] (+ bias). M % 64 == 0.
// 64x64 tile, BK=16, 256 threads, 4x4 microtile, float4 LDS reads.
// ---------------------------------------------------------------------------
__global__ __launch_bounds__(256) void sgemm64(const float* __restrict__ A,
                                               const float* __restrict__ B,
                                               const float* __restrict__ bias,
                                               float* __restrict__ C,
                                               int M, int N, int K)
{
    __shared__ float As[16][68];   // As[k][m]
    __shared__ float Bs[16][68];   // Bs[k][n]
    const int tid = threadIdx.x;
    const int tx = tid & 15, ty = tid >> 4;
    const int row0 = blockIdx.y << 6;
    const int col0 = blockIdx.x << 6;
    float acc[4][4] = {};
    for (int k0 = 0; k0 < K; k0 += 16) {
#pragma unroll
        for (int i = 0; i < 4; ++i) {
            int idx = tid + i * 256;         // 0..1023
            int m = idx >> 4, k = idx & 15;
            int kk = k0 + k;
            As[k][m] = (kk < K) ? A[(size_t)(row0 + m) * K + kk] : 0.f;
        }
#pragma unroll
        for (int i = 0; i < 4; ++i) {
            int idx = tid + i * 256;
            int k = idx >> 6, n = idx & 63;
            int kk = k0 + k, nn = col0 + n;
            Bs[k][n] = (kk < K && nn < N) ? B[(size_t)kk * N + nn] : 0.f;
        }
        __syncthreads();
#pragma unroll
        for (int kk = 0; kk < 16; ++kk) {
            float4 a4 = *(const float4*)&As[kk][ty << 2];
            float4 b4 = *(const float4*)&Bs[kk][tx << 2];
            float av[4] = {a4.x, a4.y, a4.z, a4.w};
            float bv[4] = {b4.x, b4.y, b4.z, b4.w};
#pragma unroll
            for (int i = 0; i < 4; ++i)
#pragma unroll
                for (int j = 0; j < 4; ++j)
                    acc[i][j] += av[i] * bv[j];
        }
        __syncthreads();
    }
#pragma unroll
    for (int i = 0; i < 4; ++i) {
        int r = row0 + (ty << 2) + i;
#pragma unroll
        for (int j = 0; j < 4; ++j) {
            int c = col0 + (tx << 2) + j;
            if (c < N) C[(size_t)r * N + c] = acc[i][j] + (bias ? bias[c] : 0.f);
        }
    }
}

// ---------------------------------------------------------------------------
// Per-graph adjacency GEMM: Y[g][64,HC] = A[g](64x64) @ X[g][64,HC] + bias
// AT stored transposed so both global loads & LDS writes are coalesced.
// ---------------------------------------------------------------------------
__global__ __launch_bounds__(256) void adjmm(const float* __restrict__ AT,
                                             const float* __restrict__ X,
                                             const float* __restrict__ bias,
                                             float* __restrict__ Y)
{
    __shared__ float As[64][68];   // As[k][m] = A[m][k]  (k = src, m = dst)
    __shared__ float Xs[64][68];   // Xs[k][n]
    const int g = blockIdx.y;
    const int col0 = blockIdx.x << 6;
    const int tid = threadIdx.x;
    const int tx = tid & 15, ty = tid >> 4;
    const float* ATg = AT + (size_t)g * 4096;
#pragma unroll
    for (int i = 0; i < 16; ++i) {
        int idx = tid + i * 256;          // 0..4095
        int k = idx >> 6, m = idx & 63;
        As[k][m] = ATg[idx];              // AT[k*64+m]
        int nn = col0 + m;
        Xs[k][m] = (nn < HC) ? X[((size_t)g * 64 + k) * HC + nn] : 0.f;
    }
    __syncthreads();
    float acc[4][4] = {};
#pragma unroll
    for (int kk = 0; kk < 64; ++kk) {
        float4 a4 = *(const float4*)&As[kk][ty << 2];
        float4 b4 = *(const float4*)&Xs[kk][tx << 2];
        float av[4] = {a4.x, a4.y, a4.z, a4.w};
        float bv[4] = {b4.x, b4.y, b4.z, b4.w};
#pragma unroll
        for (int i = 0; i < 4; ++i)
#pragma unroll
            for (int j = 0; j < 4; ++j)
                acc[i][j] += av[i] * bv[j];
    }
#pragma unroll
    for (int i = 0; i < 4; ++i) {
        int r = (ty << 2) + i;
#pragma unroll
        for (int j = 0; j < 4; ++j) {
            int c = col0 + (tx << 2) + j;
            if (c < HC)
                Y[((size_t)g * 64 + r) * HC + c] = acc[i][j] + bias[c];
        }
    }
}

// ---------------------------------------------------------------------------
// Mean-pool 64 nodes per graph -> hs[g][layer*HC + c]
// ---------------------------------------------------------------------------
__global__ __launch_bounds__(256) void pool_kernel(const float* __restrict__ Y,
                                                   float* __restrict__ hs, int layer)
{
    int g = blockIdx.x;
    for (int c = threadIdx.x; c < HC; c += 256) {
        float s = 0.f;
        for (int n = 0; n < 64; ++n) s += Y[((size_t)g * 64 + n) * HC + c];
        hs[(size_t)g * (HC * NLAY) + layer * HC + c] = s * (1.0f / 64.0f);
    }
}

// ---------------------------------------------------------------------------
// BatchNorm1d (training stats, biased var) over R rows; optional ReLU.
// One thread per feature; column loops are coalesced across threads.
// ---------------------------------------------------------------------------
__global__ void bn_kernel(const float* __restrict__ in, float* __restrict__ out,
                          const float* __restrict__ gamma, const float* __restrict__ beta,
                          int R, int F, int do_relu)
{
    int f = blockIdx.x * 256 + threadIdx.x;
    if (f >= F) return;
    float s = 0.f, ss = 0.f;
    for (int r = 0; r < R; ++r) {
        float v = in[(size_t)r * F + f];
        s += v; ss += v * v;
    }
    float m   = s / R;
    float var = ss / R - m * m;
    float inv = rsqrtf(var + 1e-5f) * gamma[f];
    float b   = beta[f];
    for (int r = 0; r < R; ++r) {
        float v = (in[(size_t)r * F + f] - m) * inv + b;
        if (do_relu) v = fmaxf(v, 0.f);
        out[(size_t)r * F + f] = v;
    }
}

// ---------------------------------------------------------------------------
// Gather strict-upper-triangle of per-graph x + BatchNorm (in place).
// ---------------------------------------------------------------------------
__global__ void xv_kernel(const float* __restrict__ x, const int* __restrict__ iu,
                          const int* __restrict__ ju, const float* __restrict__ gx,
                          const float* __restrict__ bx, float* __restrict__ xv)
{
    int t = blockIdx.x * 256 + threadIdx.x;
    if (t >= NTRIU) return;
    int off = iu[t] * 64 + ju[t];
    float s = 0.f, ss = 0.f;
    for (int g = 0; g < NGRAPH; ++g) {
        float v = x[(size_t)g * 4096 + off];
        xv[(size_t)g * NTRIU + t] = v;
        s += v; ss += v * v;
    }
    float m   = s / NGRAPH;
    float var = ss / NGRAPH - m * m;
    float inv = rsqrtf(var + 1e-5f) * gx[t];
    float b   = bx[t];
    for (int g = 0; g < NGRAPH; ++g)
        xv[(size_t)g * NTRIU + t] = (xv[(size_t)g * NTRIU + t] - m) * inv + b;
}

// ---------------------------------------------------------------------------
// att = sigmoid(xv . Watt + batt); z = [att*xv + (1-att)*h*0.5, h]
// ---------------------------------------------------------------------------
__global__ __launch_bounds__(256) void attz_kernel(const float* __restrict__ xv,
                                                   const float* __restrict__ h,
                                                   const float* __restrict__ Watt,
                                                   const float* __restrict__ batt,
                                                   float* __restrict__ z)
{
    int g = blockIdx.x;
    __shared__ float red[256];
    float s = 0.f;
    for (int t = threadIdx.x; t < NTRIU; t += 256)
        s += xv[(size_t)g * NTRIU + t] * Watt[t];
    red[threadIdx.x] = s;
    __syncthreads();
    for (int w = 128; w > 0; w >>= 1) {
        if (threadIdx.x < w) red[threadIdx.x] += red[threadIdx.x + w];
        __syncthreads();
    }
    float att = 1.0f / (1.0f + expf(-(red[0] + batt[0])));
    for (int t = threadIdx.x; t < NTRIU; t += 256) {
        float xvv = xv[(size_t)g * NTRIU + t];
        float hv  = h[(size_t)g * NTRIU + t];
        z[(size_t)g * DCAT + t]         = att * xvv + (1.0f - att) * hv * 0.5f;
        z[(size_t)g * DCAT + NTRIU + t] = hv;
    }
}

// ---------------------------------------------------------------------------
// Final tiny linear: out[g][0:2] = m3[g] @ Wm4 + bm4
// ---------------------------------------------------------------------------
__global__ __launch_bounds__(256) void final_kernel(const float* __restrict__ X,
                                                    const float* __restrict__ W,
                                                    const float* __restrict__ b,
                                                    float* __restrict__ out)
{
    int g = blockIdx.x;
    float s0 = 0.f, s1 = 0.f;
    for (int k = threadIdx.x; k < HID2; k += 256) {
        float v = X[(size_t)g * HID2 + k];
        s0 += v * W[k * 2 + 0];
        s1 += v * W[k * 2 + 1];
    }
    __shared__ float r0[256], r1[256];
    r0[threadIdx.x] = s0; r1[threadIdx.x] = s1;
    __syncthreads();
    for (int w = 128; w > 0; w >>= 1) {
        if (threadIdx.x < w) {
            r0[threadIdx.x] += r0[threadIdx.x + w];
            r1[threadIdx.x] += r1[threadIdx.x + w];
        }
        __syncthreads();
    }
    if (threadIdx.x == 0) {
        out[g * 2 + 0] = r0[0] + b[0];
        out[g * 2 + 1] = r1[0] + b[1];
    }
}

// ---------------------------------------------------------------------------
extern "C" void kernel_launch(void* const* d_in, const int* in_sizes, int n_in,
                              void* d_out, int out_size, void* d_ws, size_t ws_size,
                              hipStream_t stream)
{
    const float* x      = (const float*)d_in[0];
    const float* Wg0    = (const float*)d_in[1];
    const float* bg0    = (const float*)d_in[2];
    const float* WgR    = (const float*)d_in[3];
    const float* bgR    = (const float*)d_in[4];
    const float* gx     = (const float*)d_in[5];
    const float* bx     = (const float*)d_in[6];
    const float* gh     = (const float*)d_in[7];
    const float* bh     = (const float*)d_in[8];
    const float* Watt   = (const float*)d_in[9];
    const float* batt   = (const float*)d_in[10];
    const float* Wm1    = (const float*)d_in[11];
    const float* bm1    = (const float*)d_in[12];
    const float* gm1    = (const float*)d_in[13];
    const float* bem1   = (const float*)d_in[14];
    const float* Wm2    = (const float*)d_in[15];
    const float* bm2    = (const float*)d_in[16];
    const float* gm2    = (const float*)d_in[17];
    const float* bem2   = (const float*)d_in[18];
    const float* Wm3    = (const float*)d_in[19];
    const float* bm3    = (const float*)d_in[20];
    const float* gm3    = (const float*)d_in[21];
    const float* bem3   = (const float*)d_in[22];
    const float* Wm4    = (const float*)d_in[23];
    const float* bm4    = (const float*)d_in[24];
    const int*   esrc   = (const int*)d_in[25];
    const int*   edst   = (const int*)d_in[26];
    float* out = (float*)d_out;

    char* w = (char*)d_ws;
    auto alloc = [&](size_t bytes) -> char* {
        char* p = w;
        w += (bytes + 255) & ~(size_t)255;
        return p;
    };
    float* AT   = (float*)alloc((size_t)NGRAPH * 4096 * 4);
    float* buf0 = (float*)alloc((size_t)16384 * HC * 4);
    float* buf1 = (float*)alloc((size_t)16384 * HC * 4);
    float* hs   = (float*)alloc((size_t)NGRAPH * 2016 * 4);
    float* h    = (float*)alloc((size_t)NGRAPH * 2016 * 4);
    float* xv   = (float*)alloc((size_t)NGRAPH * 2016 * 4);
    float* z    = (float*)alloc((size_t)NGRAPH * DCAT * 4);
    float* m1   = (float*)alloc((size_t)NGRAPH * HID1 * 4);
    float* m2   = (float*)alloc((size_t)NGRAPH * HID2 * 4);
    float* m3   = (float*)alloc((size_t)NGRAPH * HID2 * 4);
    int*   iu   = (int*)alloc(NTRIU * 4);
    int*   ju   = (int*)alloc(NTRIU * 4);

    build_adj<<<NGRAPH, 256, 0, stream>>>(esrc, edst, AT);
    triu_idx<<<1, 64, 0, stream>>>(iu, ju);

    // GCN layer 0: x[16384,64] @ Wg0[64,504] -> buf1; adj @ buf1 + bg0 -> buf0
    sgemm64<<<dim3(8, 256), 256, 0, stream>>>(x, Wg0, nullptr, buf1, 16384, HC, 64);
    adjmm<<<dim3(8, NGRAPH), 256, 0, stream>>>(AT, buf1, bg0, buf0);
    pool_kernel<<<NGRAPH, 256, 0, stream>>>(buf0, hs, 0);

    for (int l = 1; l < NLAY; ++l) {
        sgemm64<<<dim3(8, 256), 256, 0, stream>>>(buf0, WgR + (size_t)(l - 1) * HC * HC,
                                                  nullptr, buf1, 16384, HC, HC);
        adjmm<<<dim3(8, NGRAPH), 256, 0, stream>>>(AT, buf1, bgR + (l - 1) * HC, buf0);
        pool_kernel<<<NGRAPH, 256, 0, stream>>>(buf0, hs, l);
    }

    bn_kernel<<<8, 256, 0, stream>>>(hs, h, gh, bh, NGRAPH, 2016, 0);
    xv_kernel<<<8, 256, 0, stream>>>(x, iu, ju, gx, bx, xv);
    attz_kernel<<<NGRAPH, 256, 0, stream>>>(xv, h, Watt, batt, z);

    // MLP
    sgemm64<<<dim3(16, 4), 256, 0, stream>>>(z, Wm1, bm1, m1, NGRAPH, HID1, DCAT);
    bn_kernel<<<4, 256, 0, stream>>>(m1, m1, gm1, bem1, NGRAPH, HID1, 1);
    sgemm64<<<dim3(8, 4), 256, 0, stream>>>(m1, Wm2, bm2, m2, NGRAPH, HID2, HID1);
    bn_kernel<<<2, 256, 0, stream>>>(m2, m2, gm2, bem2, NGRAPH, HID2, 1);
    sgemm64<<<dim3(8, 4), 256, 0, stream>>>(m2, Wm3, bm3, m3, NGRAPH, HID2, HID2);
    bn_kernel<<<2, 256, 0, stream>>>(m3, m3, gm3, bem3, NGRAPH, HID2, 1);
    final_kernel<<<NGRAPH, 256, 0, stream>>>(m3, Wm4, bm4, out);
}

// Round 2
// 1892.230 us; speedup vs baseline: 1.4897x; 1.4897x over previous
//
#include <hip/hip_runtime.h>
#include <math.h>

#define NGRAPH 256
#define NPG 64
#define NFEAT 64
#define HC 504
#define NLAY 4
#define EPER 1024
#define NTRIU 2016
#define DCAT 4032
#define HID1 1024
#define HID2 512

typedef __attribute__((ext_vector_type(8))) short bfrag8;   // 8 bf16 in 4 VGPRs
typedef __attribute__((ext_vector_type(4))) float f32x4;

__device__ __forceinline__ unsigned short f2b(float f) {
    union { float f; unsigned u; } v; v.f = f;
    unsigned r = (v.u + 0x7fffu + ((v.u >> 16) & 1u)) >> 16;   // RNE
    return (unsigned short)r;
}

// ---------------------------------------------------------------------------
// Build per-graph normalized adjacency, stored TRANSPOSED: AT[g][src][dst]
// ---------------------------------------------------------------------------
__global__ __launch_bounds__(256) void build_adj(const int* __restrict__ esrc,
                                                 const int* __restrict__ edst,
                                                 float* __restrict__ AT)
{
    int g = blockIdx.x;
    __shared__ float A[4096];
    __shared__ int   cnt[64];
    __shared__ float dinv[64];
    int tid = threadIdx.x;
    for (int i = tid; i < 4096; i += 256) A[i] = 0.f;
    if (tid < 64) cnt[tid] = 0;
    __syncthreads();
    for (int e = tid; e < EPER; e += 256)
        atomicAdd(&cnt[edst[(size_t)g * EPER + e] & 63], 1);
    __syncthreads();
    if (tid < 64) dinv[tid] = rsqrtf((float)cnt[tid] + 1.0f);
    __syncthreads();
    for (int e = tid; e < EPER; e += 256) {
        int s = esrc[(size_t)g * EPER + e] & 63;
        int d = edst[(size_t)g * EPER + e] & 63;
        atomicAdd(&A[s * 64 + d], dinv[s] * dinv[d]);   // transposed store
    }
    __syncthreads();
    if (tid < 64) A[tid * 64 + tid] += dinv[tid] * dinv[tid];
    __syncthreads();
    for (int i = tid; i < 4096; i += 256) AT[(size_t)g * 4096 + i] = A[i];
}

// ---------------------------------------------------------------------------
// triu(64, k=1) index tables
// ---------------------------------------------------------------------------
__global__ void triu_idx(int* __restrict__ iu, int* __restrict__ ju)
{
    int i = threadIdx.x;
    if (i >= 63) return;
    int off = 63 * i - i * (i - 1) / 2;
    for (int j = i + 1; j < 64; ++j) { iu[off] = i; ju[off] = j; ++off; }
}

// ---------------------------------------------------------------------------
// fp32 x -> bf16 copy (layer-0 A operand, [16384][64])
// ---------------------------------------------------------------------------
__global__ __launch_bounds__(256) void conv_x(const float* __restrict__ x,
                                              unsigned short* __restrict__ Xbf)
{
    int i = (blockIdx.x * 256 + threadIdx.x) * 4;   // < 16384*64
    float4 v = *(const float4*)&x[i];
    Xbf[i + 0] = f2b(v.x); Xbf[i + 1] = f2b(v.y);
    Xbf[i + 2] = f2b(v.z); Xbf[i + 3] = f2b(v.w);
}

// ---------------------------------------------------------------------------
// Weight transpose+convert: Wt[n][k] = bf16(W[k][n]), zero-padded to [NP][KP]
// W pitch = N. grid (NP/32, KP/32), block (32,8).
// ---------------------------------------------------------------------------
__global__ void convWt(const float* __restrict__ W, unsigned short* __restrict__ Wt,
                       int K, int N, int KP)
{
    __shared__ float T[32][33];
    int k0 = blockIdx.y * 32, n0 = blockIdx.x * 32;
    int tx = threadIdx.x, ty = threadIdx.y;
#pragma unroll
    for (int j = 0; j < 32; j += 8) {
        int k = k0 + ty + j, n = n0 + tx;
        T[ty + j][tx] = (k < K && n < N) ? W[(size_t)k * N + n] : 0.f;
    }
    __syncthreads();
#pragma unroll
    for (int j = 0; j < 32; j += 8) {
        int n = n0 + ty + j, k = k0 + tx;
        Wt[(size_t)n * KP + k] = f2b(T[tx][ty + j]);
    }
}

// ---------------------------------------------------------------------------
// bf16 MFMA GEMM: C[M][504] = Abf[M][KP] @ Wt[512][KP]^T   (KP in {64,512})
// 64x64 tile, 4 waves, K-step 32, double-buffered LDS, 1 barrier/iter.
// Wave w owns rows w*16..w*16+15; 4 mfma_f32_16x16x32_bf16 per K-step.
// ---------------------------------------------------------------------------
__global__ __launch_bounds__(256) void gemm_mfma(const unsigned short* __restrict__ Abf,
                                                 const unsigned short* __restrict__ Wt,
                                                 float* __restrict__ C, int KP)
{
    __shared__ unsigned short As[2][2048];   // [buf][r*32+k]  64 rows x 32 k
    __shared__ unsigned short Bs[2][2048];   // [buf][n*32+k]
    const int tid  = threadIdx.x;
    const int wave = tid >> 6, lane = tid & 63;
    const int row0 = blockIdx.y << 6, col0 = blockIdx.x << 6;
    const int NT = KP >> 5;

    // staging: thread tid copies 8 bf16 (16B): row sr, k-offset sk
    const int sr = tid >> 2;
    const int sk = (tid & 3) << 3;
    const unsigned short* gA = Abf + (size_t)(row0 + sr) * KP + sk;
    const unsigned short* gB = Wt  + (size_t)(col0 + sr) * KP + sk;

    int4 ra = *(const int4*)(const void*)gA;
    int4 rb = *(const int4*)(const void*)gB;
    *(int4*)(void*)&As[0][tid << 3] = ra;
    *(int4*)(void*)&Bs[0][tid << 3] = rb;
    __syncthreads();

    f32x4 acc0 = {0.f, 0.f, 0.f, 0.f};
    f32x4 acc1 = acc0, acc2 = acc0, acc3 = acc0;

    // fragment LDS offsets (elements)
    const int aoff = (wave * 16 + (lane & 15)) * 32 + ((lane >> 4) << 3);
    const int boff = (lane & 15) * 32 + ((lane >> 4) << 3);

    for (int t = 0; t < NT; ++t) {
        if (t + 1 < NT) {
            ra = *(const int4*)(const void*)(gA + (t + 1) * 32);
            rb = *(const int4*)(const void*)(gB + (t + 1) * 32);
        }
        const unsigned short* as = As[t & 1];
        const unsigned short* bs = Bs[t & 1];
        bfrag8 a  = *(const bfrag8*)(const void*)&as[aoff];
        bfrag8 b0 = *(const bfrag8*)(const void*)&bs[boff];
        bfrag8 b1 = *(const bfrag8*)(const void*)&bs[boff + 16 * 32];
        bfrag8 b2 = *(const bfrag8*)(const void*)&bs[boff + 32 * 32];
        bfrag8 b3 = *(const bfrag8*)(const void*)&bs[boff + 48 * 32];
        acc0 = __builtin_amdgcn_mfma_f32_16x16x32_bf16(a, b0, acc0, 0, 0, 0);
        acc1 = __builtin_amdgcn_mfma_f32_16x16x32_bf16(a, b1, acc1, 0, 0, 0);
        acc2 = __builtin_amdgcn_mfma_f32_16x16x32_bf16(a, b2, acc2, 0, 0, 0);
        acc3 = __builtin_amdgcn_mfma_f32_16x16x32_bf16(a, b3, acc3, 0, 0, 0);
        if (t + 1 < NT) {
            *(int4*)(void*)&As[(t + 1) & 1][tid << 3] = ra;
            *(int4*)(void*)&Bs[(t + 1) & 1][tid << 3] = rb;
        }
        __syncthreads();
    }

    // epilogue: D col = lane&15 (+c0*16), row = (lane>>4)*4 + reg  [m89]
    const int rbase = row0 + wave * 16 + ((lane >> 4) << 2);
    const int cbase = col0 + (lane & 15);
#pragma unroll
    for (int r = 0; r < 4; ++r) {
        int grow = rbase + r;
        if (cbase + 0  < HC) C[(size_t)grow * HC + cbase +  0] = acc0[r];
        if (cbase + 16 < HC) C[(size_t)grow * HC + cbase + 16] = acc1[r];
        if (cbase + 32 < HC) C[(size_t)grow * HC + cbase + 32] = acc2[r];
        if (cbase + 48 < HC) C[(size_t)grow * HC + cbase + 48] = acc3[r];
    }
}

// ---------------------------------------------------------------------------
// Per-graph adjacency GEMM: Y[g][64,HC] = A[g] @ X[g][64,HC] + bias
// Also emits bf16 copy (zero-padded to pitch 512) for the next MFMA layer.
// ---------------------------------------------------------------------------
__global__ __launch_bounds__(256) void adjmm(const float* __restrict__ AT,
                                             const float* __restrict__ X,
                                             const float* __restrict__ bias,
                                             float* __restrict__ Y,
                                             unsigned short* __restrict__ Ybf)
{
    __shared__ float As[64][68];   // As[k][m] = A[m][k]
    __shared__ float Xs[64][68];   // Xs[k][n]
    const int g = blockIdx.y;
    const int col0 = blockIdx.x << 6;
    const int tid = threadIdx.x;
    const int tx = tid & 15, ty = tid >> 4;
    const float* ATg = AT + (size_t)g * 4096;
    const int k  = tid >> 4;         // 0..15 (+16 per i)
    const int m4 = (tid & 15) << 2;  // 0,4,..,60
#pragma unroll
    for (int i = 0; i < 4; ++i) {
        int kk = k + i * 16;
        *(float4*)&As[kk][m4] = *(const float4*)&ATg[kk * 64 + m4];
        int nn = col0 + m4;
        float4 xv4;
        if (nn + 3 < HC) {
            xv4 = *(const float4*)&X[((size_t)g * 64 + kk) * HC + nn];
        } else {
            float t0 = (nn + 0 < HC) ? X[((size_t)g * 64 + kk) * HC + nn + 0] : 0.f;
            float t1 = (nn + 1 < HC) ? X[((size_t)g * 64 + kk) * HC + nn + 1] : 0.f;
            float t2 = (nn + 2 < HC) ? X[((size_t)g * 64 + kk) * HC + nn + 2] : 0.f;
            float t3 = (nn + 3 < HC) ? X[((size_t)g * 64 + kk) * HC + nn + 3] : 0.f;
            xv4 = make_float4(t0, t1, t2, t3);
        }
        *(float4*)&Xs[kk][m4] = xv4;
    }
    __syncthreads();
    float acc[4][4] = {};
#pragma unroll
    for (int kk = 0; kk < 64; ++kk) {
        float4 a4 = *(const float4*)&As[kk][ty << 2];
        float4 b4 = *(const float4*)&Xs[kk][tx << 2];
        float av[4] = {a4.x, a4.y, a4.z, a4.w};
        float bv[4] = {b4.x, b4.y, b4.z, b4.w};
#pragma unroll
        for (int i = 0; i < 4; ++i)
#pragma unroll
            for (int j = 0; j < 4; ++j)
                acc[i][j] += av[i] * bv[j];
    }
#pragma unroll
    for (int i = 0; i < 4; ++i) {
        int r = (ty << 2) + i;
#pragma unroll
        for (int j = 0; j < 4; ++j) {
            int c = col0 + (tx << 2) + j;
            float v = acc[i][j] + bias[c < HC ? c : 0];
            if (c < HC) Y[((size_t)g * 64 + r) * HC + c] = v;
            Ybf[((size_t)g * 64 + r) * 512 + c] = (c < HC) ? f2b(v) : (unsigned short)0;
        }
    }
}

// ---------------------------------------------------------------------------
// Mean-pool 64 nodes per graph -> hs[g][layer*HC + c]
// ---------------------------------------------------------------------------
__global__ __launch_bounds__(256) void pool_kernel(const float* __restrict__ Y,
                                                   float* __restrict__ hs, int layer)
{
    int g = blockIdx.x;
    for (int c = threadIdx.x; c < HC; c += 256) {
        float s = 0.f;
        for (int n = 0; n < 64; ++n) s += Y[((size_t)g * 64 + n) * HC + c];
        hs[(size_t)g * (HC * NLAY) + layer * HC + c] = s * (1.0f / 64.0f);
    }
}

// ---------------------------------------------------------------------------
// BatchNorm1d (training stats, biased var); optional ReLU.
// ---------------------------------------------------------------------------
__global__ void bn_kernel(const float* __restrict__ in, float* __restrict__ out,
                          const float* __restrict__ gamma, const float* __restrict__ beta,
                          int R, int F, int do_relu)
{
    int f = blockIdx.x * 256 + threadIdx.x;
    if (f >= F) return;
    float s = 0.f, ss = 0.f;
    for (int r = 0; r < R; ++r) {
        float v = in[(size_t)r * F + f];
        s += v; ss += v * v;
    }
    float m   = s / R;
    float var = ss / R - m * m;
    float inv = rsqrtf(var + 1e-5f) * gamma[f];
    float b   = beta[f];
    for (int r = 0; r < R; ++r) {
        float v = (in[(size_t)r * F + f] - m) * inv + b;
        if (do_relu) v = fmaxf(v, 0.f);
        out[(size_t)r * F + f] = v;
    }
}

// ---------------------------------------------------------------------------
// Gather strict-upper-triangle of per-graph x + BatchNorm (in place).
// ---------------------------------------------------------------------------
__global__ void xv_kernel(const float* __restrict__ x, const int* __restrict__ iu,
                          const int* __restrict__ ju, const float* __restrict__ gx,
                          const float* __restrict__ bx, float* __restrict__ xv)
{
    int t = blockIdx.x * 256 + threadIdx.x;
    if (t >= NTRIU) return;
    int off = iu[t] * 64 + ju[t];
    float s = 0.f, ss = 0.f;
    for (int g = 0; g < NGRAPH; ++g) {
        float v = x[(size_t)g * 4096 + off];
        xv[(size_t)g * NTRIU + t] = v;
        s += v; ss += v * v;
    }
    float m   = s / NGRAPH;
    float var = ss / NGRAPH - m * m;
    float inv = rsqrtf(var + 1e-5f) * gx[t];
    float b   = bx[t];
    for (int g = 0; g < NGRAPH; ++g)
        xv[(size_t)g * NTRIU + t] = (xv[(size_t)g * NTRIU + t] - m) * inv + b;
}

// ---------------------------------------------------------------------------
// att = sigmoid(xv . Watt + batt); z = [att*xv + (1-att)*h*0.5, h]
// ---------------------------------------------------------------------------
__global__ __launch_bounds__(256) void attz_kernel(const float* __restrict__ xv,
                                                   const float* __restrict__ h,
                                                   const float* __restrict__ Watt,
                                                   const float* __restrict__ batt,
                                                   float* __restrict__ z)
{
    int g = blockIdx.x;
    __shared__ float red[256];
    float s = 0.f;
    for (int t = threadIdx.x; t < NTRIU; t += 256)
        s += xv[(size_t)g * NTRIU + t] * Watt[t];
    red[threadIdx.x] = s;
    __syncthreads();
    for (int w = 128; w > 0; w >>= 1) {
        if (threadIdx.x < w) red[threadIdx.x] += red[threadIdx.x + w];
        __syncthreads();
    }
    float att = 1.0f / (1.0f + expf(-(red[0] + batt[0])));
    for (int t = threadIdx.x; t < NTRIU; t += 256) {
        float xvv = xv[(size_t)g * NTRIU + t];
        float hv  = h[(size_t)g * NTRIU + t];
        z[(size_t)g * DCAT + t]         = att * xvv + (1.0f - att) * hv * 0.5f;
        z[(size_t)g * DCAT + NTRIU + t] = hv;
    }
}

// ---------------------------------------------------------------------------
// Split-K fp32 SGEMM: P[s][M][N] partial = A[M, kb..kb+chunk] @ B[.., N]
// grid (N/64, M/64, S); chunk % 16 == 0; M,N multiples of 64; K,N mult of 4.
// ---------------------------------------------------------------------------
__global__ __launch_bounds__(256) void sgemm_sk(const float* __restrict__ A,
                                                const float* __restrict__ B,
                                                float* __restrict__ P,
                                                int M, int N, int K, int chunk)
{
    __shared__ float As[16][68];   // As[k][m]
    __shared__ float Bs[16][68];   // Bs[k][n]
    const int tid = threadIdx.x;
    const int tx = tid & 15, ty = tid >> 4;
    const int row0 = blockIdx.y << 6;
    const int col0 = blockIdx.x << 6;
    const int kb = blockIdx.z * chunk;
    const int ar  = tid >> 2;          // A staging: row 0..63
    const int aq  = (tid & 3) << 2;    // k sub-offset 0,4,8,12
    const int bk  = tid >> 4;          // B staging: k 0..15
    const int bn4 = (tid & 15) << 2;   // n sub-offset
    float acc[4][4] = {};
    for (int k0 = 0; k0 < chunk; k0 += 16) {
        float4 a4 = *(const float4*)&A[(size_t)(row0 + ar) * K + kb + k0 + aq];
        As[aq + 0][ar] = a4.x; As[aq + 1][ar] = a4.y;
        As[aq + 2][ar] = a4.z; As[aq + 3][ar] = a4.w;
        *(float4*)&Bs[bk][bn4] = *(const float4*)&B[(size_t)(kb + k0 + bk) * N + col0 + bn4];
        __syncthreads();
#pragma unroll
        for (int kk = 0; kk < 16; ++kk) {
            float4 a = *(const float4*)&As[kk][ty << 2];
            float4 b = *(const float4*)&Bs[kk][tx << 2];
            float av[4] = {a.x, a.y, a.z, a.w};
            float bv[4] = {b.x, b.y, b.z, b.w};
#pragma unroll
            for (int i = 0; i < 4; ++i)
#pragma unroll
                for (int j = 0; j < 4; ++j)
                    acc[i][j] += av[i] * bv[j];
        }
        __syncthreads();
    }
    float* Pp = P + (size_t)blockIdx.z * M * N;
#pragma unroll
    for (int i = 0; i < 4; ++i) {
        int r = row0 + (ty << 2) + i;
#pragma unroll
        for (int j = 0; j < 4; ++j)
            Pp[(size_t)r * N + col0 + (tx << 2) + j] = acc[i][j];
    }
}

// ---------------------------------------------------------------------------
// Sum S split-K partials + bias. Nmask = N-1 (N power of two).
// ---------------------------------------------------------------------------
__global__ void reduce_add(const float* __restrict__ P, const float* __restrict__ bias,
                           float* __restrict__ C, int MN, int Nmask, int S)
{
    int i = blockIdx.x * 256 + threadIdx.x;
    if (i >= MN) return;
    float s = 0.f;
    for (int t = 0; t < S; ++t) s += P[(size_t)t * MN + i];
    C[i] = s + bias[i & Nmask];
}

// ---------------------------------------------------------------------------
// Final tiny linear: out[g][0:2] = m3[g] @ Wm4 + bm4
// ---------------------------------------------------------------------------
__global__ __launch_bounds__(256) void final_kernel(const float* __restrict__ X,
                                                    const float* __restrict__ W,
                                                    const float* __restrict__ b,
                                                    float* __restrict__ out)
{
    int g = blockIdx.x;
    float s0 = 0.f, s1 = 0.f;
    for (int k = threadIdx.x; k < HID2; k += 256) {
        float v = X[(size_t)g * HID2 + k];
        s0 += v * W[k * 2 + 0];
        s1 += v * W[k * 2 + 1];
    }
    __shared__ float r0[256], r1[256];
    r0[threadIdx.x] = s0; r1[threadIdx.x] = s1;
    __syncthreads();
    for (int w = 128; w > 0; w >>= 1) {
        if (threadIdx.x < w) {
            r0[threadIdx.x] += r0[threadIdx.x + w];
            r1[threadIdx.x] += r1[threadIdx.x + w];
        }
        __syncthreads();
    }
    if (threadIdx.x == 0) {
        out[g * 2 + 0] = r0[0] + b[0];
        out[g * 2 + 1] = r1[0] + b[1];
    }
}

// ---------------------------------------------------------------------------
extern "C" void kernel_launch(void* const* d_in, const int* in_sizes, int n_in,
                              void* d_out, int out_size, void* d_ws, size_t ws_size,
                              hipStream_t stream)
{
    const float* x      = (const float*)d_in[0];
    const float* Wg0    = (const float*)d_in[1];
    const float* bg0    = (const float*)d_in[2];
    const float* WgR    = (const float*)d_in[3];
    const float* bgR    = (const float*)d_in[4];
    const float* gx     = (const float*)d_in[5];
    const float* bx     = (const float*)d_in[6];
    const float* gh     = (const float*)d_in[7];
    const float* bh     = (const float*)d_in[8];
    const float* Watt   = (const float*)d_in[9];
    const float* batt   = (const float*)d_in[10];
    const float* Wm1    = (const float*)d_in[11];
    const float* bm1    = (const float*)d_in[12];
    const float* gm1    = (const float*)d_in[13];
    const float* bem1   = (const float*)d_in[14];
    const float* Wm2    = (const float*)d_in[15];
    const float* bm2    = (const float*)d_in[16];
    const float* gm2    = (const float*)d_in[17];
    const float* bem2   = (const float*)d_in[18];
    const float* Wm3    = (const float*)d_in[19];
    const float* bm3    = (const float*)d_in[20];
    const float* gm3    = (const float*)d_in[21];
    const float* bem3   = (const float*)d_in[22];
    const float* Wm4    = (const float*)d_in[23];
    const float* bm4    = (const float*)d_in[24];
    const int*   esrc   = (const int*)d_in[25];
    const int*   edst   = (const int*)d_in[26];
    float* out = (float*)d_out;

    char* w = (char*)d_ws;
    auto alloc = [&](size_t bytes) -> char* {
        char* p = w;
        w += (bytes + 255) & ~(size_t)255;
        return p;
    };
    float*          AT   = (float*)alloc((size_t)NGRAPH * 4096 * 4);
    float*          xw   = (float*)alloc((size_t)16384 * HC * 4);       // mfma out / P alias
    float*          buf0 = (float*)alloc((size_t)16384 * HC * 4);       // adjmm fp32 out
    unsigned short* Ybf  = (unsigned short*)alloc((size_t)16384 * 512 * 2);
    unsigned short* Xbf  = (unsigned short*)alloc((size_t)16384 * 64 * 2);
    unsigned short* Wt0  = (unsigned short*)alloc((size_t)512 * 64 * 2);
    unsigned short* Wt1  = (unsigned short*)alloc((size_t)512 * 512 * 2);
    unsigned short* Wt2  = (unsigned short*)alloc((size_t)512 * 512 * 2);
    unsigned short* Wt3  = (unsigned short*)alloc((size_t)512 * 512 * 2);
    float*          hs   = (float*)alloc((size_t)NGRAPH * 2016 * 4);
    float*          h    = (float*)alloc((size_t)NGRAPH * 2016 * 4);
    float*          xv   = (float*)alloc((size_t)NGRAPH * 2016 * 4);
    float*          z    = (float*)alloc((size_t)NGRAPH * DCAT * 4);
    float*          m1   = (float*)alloc((size_t)NGRAPH * HID1 * 4);
    float*          m2   = (float*)alloc((size_t)NGRAPH * HID2 * 4);
    float*          m3   = (float*)alloc((size_t)NGRAPH * HID2 * 4);
    int*            iu   = (int*)alloc(NTRIU * 4);
    int*            ju   = (int*)alloc(NTRIU * 4);
    float*          P    = xw;   // split-K partials reuse xw (dead after GCN)

    build_adj<<<NGRAPH, 256, 0, stream>>>(esrc, edst, AT);
    triu_idx<<<1, 64, 0, stream>>>(iu, ju);
    conv_x<<<1024, 256, 0, stream>>>(x, Xbf);
    convWt<<<dim3(16, 2),  dim3(32, 8), 0, stream>>>(Wg0, Wt0, 64, HC, 64);
    convWt<<<dim3(16, 16), dim3(32, 8), 0, stream>>>(WgR + 0 * HC * HC, Wt1, HC, HC, 512);
    convWt<<<dim3(16, 16), dim3(32, 8), 0, stream>>>(WgR + 1 * HC * HC, Wt2, HC, HC, 512);
    convWt<<<dim3(16, 16), dim3(32, 8), 0, stream>>>(WgR + 2 * HC * HC, Wt3, HC, HC, 512);

    // GCN layers: xw = A@W (mfma), buf0 = Adj@xw + b (fp32), pool
    gemm_mfma<<<dim3(8, 256), 256, 0, stream>>>(Xbf, Wt0, xw, 64);
    adjmm<<<dim3(8, NGRAPH), 256, 0, stream>>>(AT, xw, bg0, buf0, Ybf);
    pool_kernel<<<NGRAPH, 256, 0, stream>>>(buf0, hs, 0);
    const unsigned short* Wts[3] = {Wt1, Wt2, Wt3};
    for (int l = 1; l < NLAY; ++l) {
        gemm_mfma<<<dim3(8, 256), 256, 0, stream>>>(Ybf, Wts[l - 1], xw, 512);
        adjmm<<<dim3(8, NGRAPH), 256, 0, stream>>>(AT, xw, bgR + (l - 1) * HC, buf0, Ybf);
        pool_kernel<<<NGRAPH, 256, 0, stream>>>(buf0, hs, l);
    }

    bn_kernel<<<8, 256, 0, stream>>>(hs, h, gh, bh, NGRAPH, 2016, 0);
    xv_kernel<<<8, 256, 0, stream>>>(x, iu, ju, gx, bx, xv);
    attz_kernel<<<NGRAPH, 256, 0, stream>>>(xv, h, Watt, batt, z);

    // MLP with split-K fp32 (P reuses xw: 12*256*1024*4 = 12.6MB < 33MB)
    sgemm_sk<<<dim3(16, 4, 12), 256, 0, stream>>>(z, Wm1, P, NGRAPH, HID1, DCAT, 336);
    reduce_add<<<1024, 256, 0, stream>>>(P, bm1, m1, NGRAPH * HID1, HID1 - 1, 12);
    bn_kernel<<<4, 256, 0, stream>>>(m1, m1, gm1, bem1, NGRAPH, HID1, 1);

    sgemm_sk<<<dim3(8, 4, 8), 256, 0, stream>>>(m1, Wm2, P, NGRAPH, HID2, HID1, 128);
    reduce_add<<<512, 256, 0, stream>>>(P, bm2, m2, NGRAPH * HID2, HID2 - 1, 8);
    bn_kernel<<<2, 256, 0, stream>>>(m2, m2, gm2, bem2, NGRAPH, HID2, 1);

    sgemm_sk<<<dim3(8, 4, 8), 256, 0, stream>>>(m2, Wm3, P, NGRAPH, HID2, HID2, 64);
    reduce_add<<<512, 256, 0, stream>>>(P, bm3, m3, NGRAPH * HID2, HID2 - 1, 8);
    bn_kernel<<<2, 256, 0, stream>>>(m3, m3, gm3, bem3, NGRAPH, HID2, 1);

    final_kernel<<<NGRAPH, 256, 0, stream>>>(m3, Wm4, bm4, out);
}

// Round 3
// 716.953 us; speedup vs baseline: 3.9316x; 2.6393x over previous
//
#include <hip/hip_runtime.h>
#include <math.h>

#define NGRAPH 256
#define NPG 64
#define NFEAT 64
#define HC 504
#define NLAY 4
#define EPER 1024
#define NTRIU 2016
#define DCAT 4032
#define HID1 1024
#define HID2 512

typedef __attribute__((ext_vector_type(8))) short bfrag8;   // 8 bf16 in 4 VGPRs
typedef __attribute__((ext_vector_type(4))) float f32x4;

struct us4 { unsigned short a, b, c, d; };

__device__ __forceinline__ unsigned short f2b(float f) {
    union { float f; unsigned u; } v; v.f = f;
    unsigned r = (v.u + 0x7fffu + ((v.u >> 16) & 1u)) >> 16;   // RNE
    return (unsigned short)r;
}
__device__ __forceinline__ float b2f(unsigned short h) {
    union { unsigned u; float f; } v; v.u = ((unsigned)h) << 16;
    return v.f;
}

// ---------------------------------------------------------------------------
// Build per-graph normalized adjacency A[dst][src], emitted as split bf16:
// Ahi = bf16(A), Alo = bf16(A - Ahi)  (~16-bit mantissa total)
// ---------------------------------------------------------------------------
__global__ __launch_bounds__(256) void build_adj(const int* __restrict__ esrc,
                                                 const int* __restrict__ edst,
                                                 unsigned short* __restrict__ Ahi,
                                                 unsigned short* __restrict__ Alo)
{
    int g = blockIdx.x;
    __shared__ float A[4096];
    __shared__ int   cnt[64];
    __shared__ float dinv[64];
    int tid = threadIdx.x;
    for (int i = tid; i < 4096; i += 256) A[i] = 0.f;
    if (tid < 64) cnt[tid] = 0;
    __syncthreads();
    for (int e = tid; e < EPER; e += 256)
        atomicAdd(&cnt[edst[(size_t)g * EPER + e] & 63], 1);
    __syncthreads();
    if (tid < 64) dinv[tid] = rsqrtf((float)cnt[tid] + 1.0f);
    __syncthreads();
    for (int e = tid; e < EPER; e += 256) {
        int s = esrc[(size_t)g * EPER + e] & 63;
        int d = edst[(size_t)g * EPER + e] & 63;
        atomicAdd(&A[d * 64 + s], dinv[s] * dinv[d]);   // row-major [dst][src]
    }
    __syncthreads();
    if (tid < 64) A[tid * 64 + tid] += dinv[tid] * dinv[tid];
    __syncthreads();
    for (int i = tid; i < 4096; i += 256) {
        float v = A[i];
        unsigned short hi = f2b(v);
        Ahi[(size_t)g * 4096 + i] = hi;
        Alo[(size_t)g * 4096 + i] = f2b(v - b2f(hi));
    }
}

// ---------------------------------------------------------------------------
// triu(64, k=1) index tables
// ---------------------------------------------------------------------------
__global__ void triu_idx(int* __restrict__ iu, int* __restrict__ ju)
{
    int i = threadIdx.x;
    if (i >= 63) return;
    int off = 63 * i - i * (i - 1) / 2;
    for (int j = i + 1; j < 64; ++j) { iu[off] = i; ju[off] = j; ++off; }
}

// ---------------------------------------------------------------------------
// fp32 x -> bf16 copy (layer-0 A operand, [16384][64])
// ---------------------------------------------------------------------------
__global__ __launch_bounds__(256) void conv_x(const float* __restrict__ x,
                                              unsigned short* __restrict__ Xbf)
{
    int i = (blockIdx.x * 256 + threadIdx.x) * 4;   // < 16384*64
    float4 v = *(const float4*)&x[i];
    Xbf[i + 0] = f2b(v.x); Xbf[i + 1] = f2b(v.y);
    Xbf[i + 2] = f2b(v.z); Xbf[i + 3] = f2b(v.w);
}

// ---------------------------------------------------------------------------
// Weight transpose+convert: Wt[n][k] = bf16(W[k][n]), zero-padded to [512][KP]
// ---------------------------------------------------------------------------
__global__ void convWt(const float* __restrict__ W, unsigned short* __restrict__ Wt,
                       int K, int N, int KP)
{
    __shared__ float T[32][33];
    int k0 = blockIdx.y * 32, n0 = blockIdx.x * 32;
    int tx = threadIdx.x, ty = threadIdx.y;
#pragma unroll
    for (int j = 0; j < 32; j += 8) {
        int k = k0 + ty + j, n = n0 + tx;
        T[ty + j][tx] = (k < K && n < N) ? W[(size_t)k * N + n] : 0.f;
    }
    __syncthreads();
#pragma unroll
    for (int j = 0; j < 32; j += 8) {
        int n = n0 + ty + j, k = k0 + tx;
        Wt[(size_t)n * KP + k] = f2b(T[tx][ty + j]);
    }
}

// ---------------------------------------------------------------------------
// bf16 MFMA feature GEMM: C = Abf[M][KP] @ Wt[512][KP]^T, written TRANSPOSED
// per graph as bf16: Xt[g][col(512)][row(64)].  KP in {64,512}.
// 64x64 tile, 4 waves, K-step 32, double-buffered LDS.
// ---------------------------------------------------------------------------
__global__ __launch_bounds__(256) void gemm_mfma(const unsigned short* __restrict__ Abf,
                                                 const unsigned short* __restrict__ Wt,
                                                 unsigned short* __restrict__ Xt,
                                                 int KP)
{
    __shared__ unsigned short As[2][2048];   // [buf][r*32+k]
    __shared__ unsigned short Bs[2][2048];   // [buf][n*32+k]
    const int tid  = threadIdx.x;
    const int wave = tid >> 6, lane = tid & 63;
    const int g = blockIdx.y, col0 = blockIdx.x << 6;
    const int NT = KP >> 5;

    const int sr = tid >> 2;
    const int sk = (tid & 3) << 3;
    const unsigned short* gA = Abf + ((size_t)g * 64 + sr) * KP + sk;
    const unsigned short* gB = Wt  + (size_t)(col0 + sr) * KP + sk;

    int4 ra = *(const int4*)(const void*)gA;
    int4 rb = *(const int4*)(const void*)gB;
    *(int4*)(void*)&As[0][tid << 3] = ra;
    *(int4*)(void*)&Bs[0][tid << 3] = rb;
    __syncthreads();

    f32x4 acc0 = {0.f, 0.f, 0.f, 0.f};
    f32x4 acc1 = acc0, acc2 = acc0, acc3 = acc0;

    const int aoff = (wave * 16 + (lane & 15)) * 32 + ((lane >> 4) << 3);
    const int boff = (lane & 15) * 32 + ((lane >> 4) << 3);

    for (int t = 0; t < NT; ++t) {
        if (t + 1 < NT) {
            ra = *(const int4*)(const void*)(gA + (t + 1) * 32);
            rb = *(const int4*)(const void*)(gB + (t + 1) * 32);
        }
        const unsigned short* as = As[t & 1];
        const unsigned short* bs = Bs[t & 1];
        bfrag8 a  = *(const bfrag8*)(const void*)&as[aoff];
        bfrag8 b0 = *(const bfrag8*)(const void*)&bs[boff];
        bfrag8 b1 = *(const bfrag8*)(const void*)&bs[boff + 16 * 32];
        bfrag8 b2 = *(const bfrag8*)(const void*)&bs[boff + 32 * 32];
        bfrag8 b3 = *(const bfrag8*)(const void*)&bs[boff + 48 * 32];
        acc0 = __builtin_amdgcn_mfma_f32_16x16x32_bf16(a, b0, acc0, 0, 0, 0);
        acc1 = __builtin_amdgcn_mfma_f32_16x16x32_bf16(a, b1, acc1, 0, 0, 0);
        acc2 = __builtin_amdgcn_mfma_f32_16x16x32_bf16(a, b2, acc2, 0, 0, 0);
        acc3 = __builtin_amdgcn_mfma_f32_16x16x32_bf16(a, b3, acc3, 0, 0, 0);
        if (t + 1 < NT) {
            *(int4*)(void*)&As[(t + 1) & 1][tid << 3] = ra;
            *(int4*)(void*)&Bs[(t + 1) & 1][tid << 3] = rb;
        }
        __syncthreads();
    }

    // D layout: col = lane&15 (+16 per acc), row = (lane>>4)*4 + reg  [m89]
    // Store transposed bf16: Xt[g][col][row], 4 consecutive rows -> 8B store.
    unsigned short* Xg = Xt + (size_t)g * 32768;
    const int rloc = wave * 16 + ((lane >> 4) << 2);
    const int cb = col0 + (lane & 15);
    f32x4 accs[4] = {acc0, acc1, acc2, acc3};
#pragma unroll
    for (int j = 0; j < 4; ++j) {
        us4 p;
        p.a = f2b(accs[j][0]); p.b = f2b(accs[j][1]);
        p.c = f2b(accs[j][2]); p.d = f2b(accs[j][3]);
        *(us4*)(void*)&Xg[(cb + j * 16) * 64 + rloc] = p;
    }
}

// ---------------------------------------------------------------------------
// Adjacency GCN step (MFMA, split-bf16 A):
//   Y[g] = A[g](64x64) @ X[g](64x512) + bias; emits bf16 Ybf[node][512]
//   and fused mean-pool into hs[g][layer*504 + c].
// A operand: Ahi/Alo [g][dst][src]; B operand: Xt[g][feat][node].
// grid (8 col-chunks, 256 graphs), 4 waves: wave w -> rows w*16..w*16+15.
// ---------------------------------------------------------------------------
__global__ __launch_bounds__(256) void adjmm_gcn(const unsigned short* __restrict__ Ahi,
                                                 const unsigned short* __restrict__ Alo,
                                                 const unsigned short* __restrict__ Xt,
                                                 const float* __restrict__ bias,
                                                 unsigned short* __restrict__ Ybf,
                                                 float* __restrict__ hs, int layer)
{
    const int g = blockIdx.y, c0 = blockIdx.x << 6;
    const int tid = threadIdx.x, w = tid >> 6, lane = tid & 63;
    const int lm = lane & 15, lh = lane >> 4;
    __shared__ float pb[4][64];

    const unsigned short* Ah = Ahi + (size_t)g * 4096;
    const unsigned short* Al = Alo + (size_t)g * 4096;
    const int arow = (w * 16 + lm) * 64 + (lh << 3);
    bfrag8 ah0 = *(const bfrag8*)(const void*)&Ah[arow];
    bfrag8 ah1 = *(const bfrag8*)(const void*)&Ah[arow + 32];
    bfrag8 al0 = *(const bfrag8*)(const void*)&Al[arow];
    bfrag8 al1 = *(const bfrag8*)(const void*)&Al[arow + 32];

    const unsigned short* Xg = Xt + (size_t)g * 32768;
    f32x4 acc[4];
#pragma unroll
    for (int nt = 0; nt < 4; ++nt) acc[nt] = (f32x4){0.f, 0.f, 0.f, 0.f};

#pragma unroll
    for (int nt = 0; nt < 4; ++nt) {
        const int col = c0 + nt * 16 + lm;
        bfrag8 b0 = *(const bfrag8*)(const void*)&Xg[col * 64 + (lh << 3)];
        bfrag8 b1 = *(const bfrag8*)(const void*)&Xg[col * 64 + 32 + (lh << 3)];
        acc[nt] = __builtin_amdgcn_mfma_f32_16x16x32_bf16(ah0, b0, acc[nt], 0, 0, 0);
        acc[nt] = __builtin_amdgcn_mfma_f32_16x16x32_bf16(al0, b0, acc[nt], 0, 0, 0);
        acc[nt] = __builtin_amdgcn_mfma_f32_16x16x32_bf16(ah1, b1, acc[nt], 0, 0, 0);
        acc[nt] = __builtin_amdgcn_mfma_f32_16x16x32_bf16(al1, b1, acc[nt], 0, 0, 0);
    }

    // epilogue: bias, bf16 store, pool partial
    const int rbase = w * 16 + (lh << 2);
#pragma unroll
    for (int nt = 0; nt < 4; ++nt) {
        const int col = c0 + nt * 16 + lm;
        const float bv = (col < HC) ? bias[col] : 0.f;
#pragma unroll
        for (int r = 0; r < 4; ++r) {
            acc[nt][r] += bv;   // pad cols: Xt zero-padded -> acc==0, bv==0
            Ybf[((size_t)g * 64 + rbase + r) * 512 + col] = f2b(acc[nt][r]);
        }
        float cs = acc[nt][0] + acc[nt][1] + acc[nt][2] + acc[nt][3];
        cs += __shfl_xor(cs, 16, 64);
        cs += __shfl_xor(cs, 32, 64);
        if (lh == 0) pb[w][nt * 16 + lm] = cs;
    }
    __syncthreads();
    if (tid < 64) {
        int col = c0 + tid;
        if (col < HC) {
            float s = pb[0][tid] + pb[1][tid] + pb[2][tid] + pb[3][tid];
            hs[(size_t)g * (HC * NLAY) + layer * HC + col] = s * (1.0f / 64.0f);
        }
    }
}

// ---------------------------------------------------------------------------
// BatchNorm1d (training stats, biased var); optional ReLU.
// ---------------------------------------------------------------------------
__global__ void bn_kernel(const float* __restrict__ in, float* __restrict__ out,
                          const float* __restrict__ gamma, const float* __restrict__ beta,
                          int R, int F, int do_relu)
{
    int f = blockIdx.x * 256 + threadIdx.x;
    if (f >= F) return;
    float s = 0.f, ss = 0.f;
    for (int r = 0; r < R; ++r) {
        float v = in[(size_t)r * F + f];
        s += v; ss += v * v;
    }
    float m   = s / R;
    float var = ss / R - m * m;
    float inv = rsqrtf(var + 1e-5f) * gamma[f];
    float b   = beta[f];
    for (int r = 0; r < R; ++r) {
        float v = (in[(size_t)r * F + f] - m) * inv + b;
        if (do_relu) v = fmaxf(v, 0.f);
        out[(size_t)r * F + f] = v;
    }
}

// ---------------------------------------------------------------------------
// Gather strict-upper-triangle of per-graph x + BatchNorm (in place).
// ---------------------------------------------------------------------------
__global__ void xv_kernel(const float* __restrict__ x, const int* __restrict__ iu,
                          const int* __restrict__ ju, const float* __restrict__ gx,
                          const float* __restrict__ bx, float* __restrict__ xv)
{
    int t = blockIdx.x * 256 + threadIdx.x;
    if (t >= NTRIU) return;
    int off = iu[t] * 64 + ju[t];
    float s = 0.f, ss = 0.f;
    for (int g = 0; g < NGRAPH; ++g) {
        float v = x[(size_t)g * 4096 + off];
        xv[(size_t)g * NTRIU + t] = v;
        s += v; ss += v * v;
    }
    float m   = s / NGRAPH;
    float var = ss / NGRAPH - m * m;
    float inv = rsqrtf(var + 1e-5f) * gx[t];
    float b   = bx[t];
    for (int g = 0; g < NGRAPH; ++g)
        xv[(size_t)g * NTRIU + t] = (xv[(size_t)g * NTRIU + t] - m) * inv + b;
}

// ---------------------------------------------------------------------------
// att = sigmoid(xv . Watt + batt); z = [att*xv + (1-att)*h*0.5, h]
// ---------------------------------------------------------------------------
__global__ __launch_bounds__(256) void attz_kernel(const float* __restrict__ xv,
                                                   const float* __restrict__ h,
                                                   const float* __restrict__ Watt,
                                                   const float* __restrict__ batt,
                                                   float* __restrict__ z)
{
    int g = blockIdx.x;
    __shared__ float red[256];
    float s = 0.f;
    for (int t = threadIdx.x; t < NTRIU; t += 256)
        s += xv[(size_t)g * NTRIU + t] * Watt[t];
    red[threadIdx.x] = s;
    __syncthreads();
    for (int w = 128; w > 0; w >>= 1) {
        if (threadIdx.x < w) red[threadIdx.x] += red[threadIdx.x + w];
        __syncthreads();
    }
    float att = 1.0f / (1.0f + expf(-(red[0] + batt[0])));
    for (int t = threadIdx.x; t < NTRIU; t += 256) {
        float xvv = xv[(size_t)g * NTRIU + t];
        float hv  = h[(size_t)g * NTRIU + t];
        z[(size_t)g * DCAT + t]         = att * xvv + (1.0f - att) * hv * 0.5f;
        z[(size_t)g * DCAT + NTRIU + t] = hv;
    }
}

// ---------------------------------------------------------------------------
// Split-K fp32 SGEMM: P[s][M][N] partial = A[M, kb..kb+chunk] @ B[.., N]
// ---------------------------------------------------------------------------
__global__ __launch_bounds__(256) void sgemm_sk(const float* __restrict__ A,
                                                const float* __restrict__ B,
                                                float* __restrict__ P,
                                                int M, int N, int K, int chunk)
{
    __shared__ float As[16][68];
    __shared__ float Bs[16][68];
    const int tid = threadIdx.x;
    const int tx = tid & 15, ty = tid >> 4;
    const int row0 = blockIdx.y << 6;
    const int col0 = blockIdx.x << 6;
    const int kb = blockIdx.z * chunk;
    const int ar  = tid >> 2;
    const int aq  = (tid & 3) << 2;
    const int bk  = tid >> 4;
    const int bn4 = (tid & 15) << 2;
    float acc[4][4] = {};
    for (int k0 = 0; k0 < chunk; k0 += 16) {
        float4 a4 = *(const float4*)&A[(size_t)(row0 + ar) * K + kb + k0 + aq];
        As[aq + 0][ar] = a4.x; As[aq + 1][ar] = a4.y;
        As[aq + 2][ar] = a4.z; As[aq + 3][ar] = a4.w;
        *(float4*)&Bs[bk][bn4] = *(const float4*)&B[(size_t)(kb + k0 + bk) * N + col0 + bn4];
        __syncthreads();
#pragma unroll
        for (int kk = 0; kk < 16; ++kk) {
            float4 a = *(const float4*)&As[kk][ty << 2];
            float4 b = *(const float4*)&Bs[kk][tx << 2];
            float av[4] = {a.x, a.y, a.z, a.w};
            float bv[4] = {b.x, b.y, b.z, b.w};
#pragma unroll
            for (int i = 0; i < 4; ++i)
#pragma unroll
                for (int j = 0; j < 4; ++j)
                    acc[i][j] += av[i] * bv[j];
        }
        __syncthreads();
    }
    float* Pp = P + (size_t)blockIdx.z * M * N;
#pragma unroll
    for (int i = 0; i < 4; ++i) {
        int r = row0 + (ty << 2) + i;
#pragma unroll
        for (int j = 0; j < 4; ++j)
            Pp[(size_t)r * N + col0 + (tx << 2) + j] = acc[i][j];
    }
}

// ---------------------------------------------------------------------------
// Sum S split-K partials + bias. Nmask = N-1 (N power of two).
// ---------------------------------------------------------------------------
__global__ void reduce_add(const float* __restrict__ P, const float* __restrict__ bias,
                           float* __restrict__ C, int MN, int Nmask, int S)
{
    int i = blockIdx.x * 256 + threadIdx.x;
    if (i >= MN) return;
    float s = 0.f;
    for (int t = 0; t < S; ++t) s += P[(size_t)t * MN + i];
    C[i] = s + bias[i & Nmask];
}

// ---------------------------------------------------------------------------
// Final tiny linear: out[g][0:2] = m3[g] @ Wm4 + bm4
// ---------------------------------------------------------------------------
__global__ __launch_bounds__(256) void final_kernel(const float* __restrict__ X,
                                                    const float* __restrict__ W,
                                                    const float* __restrict__ b,
                                                    float* __restrict__ out)
{
    int g = blockIdx.x;
    float s0 = 0.f, s1 = 0.f;
    for (int k = threadIdx.x; k < HID2; k += 256) {
        float v = X[(size_t)g * HID2 + k];
        s0 += v * W[k * 2 + 0];
        s1 += v * W[k * 2 + 1];
    }
    __shared__ float r0[256], r1[256];
    r0[threadIdx.x] = s0; r1[threadIdx.x] = s1;
    __syncthreads();
    for (int w = 128; w > 0; w >>= 1) {
        if (threadIdx.x < w) {
            r0[threadIdx.x] += r0[threadIdx.x + w];
            r1[threadIdx.x] += r1[threadIdx.x + w];
        }
        __syncthreads();
    }
    if (threadIdx.x == 0) {
        out[g * 2 + 0] = r0[0] + b[0];
        out[g * 2 + 1] = r1[0] + b[1];
    }
}

// ---------------------------------------------------------------------------
extern "C" void kernel_launch(void* const* d_in, const int* in_sizes, int n_in,
                              void* d_out, int out_size, void* d_ws, size_t ws_size,
                              hipStream_t stream)
{
    const float* x      = (const float*)d_in[0];
    const float* Wg0    = (const float*)d_in[1];
    const float* bg0    = (const float*)d_in[2];
    const float* WgR    = (const float*)d_in[3];
    const float* bgR    = (const float*)d_in[4];
    const float* gx     = (const float*)d_in[5];
    const float* bx     = (const float*)d_in[6];
    const float* gh     = (const float*)d_in[7];
    const float* bh     = (const float*)d_in[8];
    const float* Watt   = (const float*)d_in[9];
    const float* batt   = (const float*)d_in[10];
    const float* Wm1    = (const float*)d_in[11];
    const float* bm1    = (const float*)d_in[12];
    const float* gm1    = (const float*)d_in[13];
    const float* bem1   = (const float*)d_in[14];
    const float* Wm2    = (const float*)d_in[15];
    const float* bm2    = (const float*)d_in[16];
    const float* gm2    = (const float*)d_in[17];
    const float* bem2   = (const float*)d_in[18];
    const float* Wm3    = (const float*)d_in[19];
    const float* bm3    = (const float*)d_in[20];
    const float* gm3    = (const float*)d_in[21];
    const float* bem3   = (const float*)d_in[22];
    const float* Wm4    = (const float*)d_in[23];
    const float* bm4    = (const float*)d_in[24];
    const int*   esrc   = (const int*)d_in[25];
    const int*   edst   = (const int*)d_in[26];
    float* out = (float*)d_out;

    char* w = (char*)d_ws;
    auto alloc = [&](size_t bytes) -> char* {
        char* p = w;
        w += (bytes + 255) & ~(size_t)255;
        return p;
    };
    unsigned short* Ahi  = (unsigned short*)alloc((size_t)NGRAPH * 4096 * 2);
    unsigned short* Alo  = (unsigned short*)alloc((size_t)NGRAPH * 4096 * 2);
    unsigned short* Xt   = (unsigned short*)alloc((size_t)NGRAPH * 32768 * 2); // 16.8MB
    unsigned short* Ybf  = (unsigned short*)alloc((size_t)16384 * 512 * 2);
    unsigned short* Xbf  = (unsigned short*)alloc((size_t)16384 * 64 * 2);
    unsigned short* Wt0  = (unsigned short*)alloc((size_t)512 * 64 * 2);
    unsigned short* Wt1  = (unsigned short*)alloc((size_t)512 * 512 * 2);
    unsigned short* Wt2  = (unsigned short*)alloc((size_t)512 * 512 * 2);
    unsigned short* Wt3  = (unsigned short*)alloc((size_t)512 * 512 * 2);
    float*          hs   = (float*)alloc((size_t)NGRAPH * 2016 * 4);
    float*          h    = (float*)alloc((size_t)NGRAPH * 2016 * 4);
    float*          xv   = (float*)alloc((size_t)NGRAPH * 2016 * 4);
    float*          z    = (float*)alloc((size_t)NGRAPH * DCAT * 4);
    float*          m1   = (float*)alloc((size_t)NGRAPH * HID1 * 4);
    float*          m2   = (float*)alloc((size_t)NGRAPH * HID2 * 4);
    float*          m3   = (float*)alloc((size_t)NGRAPH * HID2 * 4);
    int*            iu   = (int*)alloc(NTRIU * 4);
    int*            ju   = (int*)alloc(NTRIU * 4);
    float*          P    = (float*)Xt;   // split-K partials reuse Xt (dead after GCN)

    build_adj<<<NGRAPH, 256, 0, stream>>>(esrc, edst, Ahi, Alo);
    triu_idx<<<1, 64, 0, stream>>>(iu, ju);
    conv_x<<<1024, 256, 0, stream>>>(x, Xbf);
    convWt<<<dim3(16, 2),  dim3(32, 8), 0, stream>>>(Wg0, Wt0, 64, HC, 64);
    convWt<<<dim3(16, 16), dim3(32, 8), 0, stream>>>(WgR + 0 * HC * HC, Wt1, HC, HC, 512);
    convWt<<<dim3(16, 16), dim3(32, 8), 0, stream>>>(WgR + 1 * HC * HC, Wt2, HC, HC, 512);
    convWt<<<dim3(16, 16), dim3(32, 8), 0, stream>>>(WgR + 2 * HC * HC, Wt3, HC, HC, 512);

    // GCN layers: Xt = (cur @ W)^T bf16 (mfma), then adjacency+pool (mfma)
    gemm_mfma<<<dim3(8, 256), 256, 0, stream>>>(Xbf, Wt0, Xt, 64);
    adjmm_gcn<<<dim3(8, 256), 256, 0, stream>>>(Ahi, Alo, Xt, bg0, Ybf, hs, 0);
    const unsigned short* Wts[3] = {Wt1, Wt2, Wt3};
    for (int l = 1; l < NLAY; ++l) {
        gemm_mfma<<<dim3(8, 256), 256, 0, stream>>>(Ybf, Wts[l - 1], Xt, 512);
        adjmm_gcn<<<dim3(8, 256), 256, 0, stream>>>(Ahi, Alo, Xt, bgR + (l - 1) * HC, Ybf, hs, l);
    }

    bn_kernel<<<8, 256, 0, stream>>>(hs, h, gh, bh, NGRAPH, 2016, 0);
    xv_kernel<<<8, 256, 0, stream>>>(x, iu, ju, gx, bx, xv);
    attz_kernel<<<NGRAPH, 256, 0, stream>>>(xv, h, Watt, batt, z);

    // MLP with split-K fp32 (P reuses Xt: 12*256*1024*4 = 12.6MB < 16.8MB)
    sgemm_sk<<<dim3(16, 4, 12), 256, 0, stream>>>(z, Wm1, P, NGRAPH, HID1, DCAT, 336);
    reduce_add<<<1024, 256, 0, stream>>>(P, bm1, m1, NGRAPH * HID1, HID1 - 1, 12);
    bn_kernel<<<4, 256, 0, stream>>>(m1, m1, gm1, bem1, NGRAPH, HID1, 1);

    sgemm_sk<<<dim3(8, 4, 8), 256, 0, stream>>>(m1, Wm2, P, NGRAPH, HID2, HID1, 128);
    reduce_add<<<512, 256, 0, stream>>>(P, bm2, m2, NGRAPH * HID2, HID2 - 1, 8);
    bn_kernel<<<2, 256, 0, stream>>>(m2, m2, gm2, bem2, NGRAPH, HID2, 1);

    sgemm_sk<<<dim3(8, 4, 8), 256, 0, stream>>>(m2, Wm3, P, NGRAPH, HID2, HID2, 64);
    reduce_add<<<512, 256, 0, stream>>>(P, bm3, m3, NGRAPH * HID2, HID2 - 1, 8);
    bn_kernel<<<2, 256, 0, stream>>>(m3, m3, gm3, bem3, NGRAPH, HID2, 1);

    final_kernel<<<NGRAPH, 256, 0, stream>>>(m3, Wm4, bm4, out);
}

// Round 4
// 315.542 us; speedup vs baseline: 8.9331x; 2.2721x over previous
//
#include <hip/hip_runtime.h>
#include <math.h>

#define NGRAPH 256
#define NPG 64
#define NFEAT 64
#define HC 504
#define NLAY 4
#define EPER 1024
#define NTRIU 2016
#define DCAT 4032
#define HID1 1024
#define HID2 512

typedef __attribute__((ext_vector_type(8))) short bfrag8;   // 8 bf16 in 4 VGPRs
typedef __attribute__((ext_vector_type(4))) float f32x4;

struct us4 { unsigned short a, b, c, d; };

__device__ __forceinline__ unsigned short f2b(float f) {
    union { float f; unsigned u; } v; v.f = f;
    unsigned r = (v.u + 0x7fffu + ((v.u >> 16) & 1u)) >> 16;   // RNE
    return (unsigned short)r;
}
__device__ __forceinline__ float b2f(unsigned short h) {
    union { unsigned u; float f; } v; v.u = ((unsigned)h) << 16;
    return v.f;
}

// ---------------------------------------------------------------------------
// Build per-graph normalized adjacency A[dst][src], emitted as split bf16:
// Ahi = bf16(A), Alo = bf16(A - Ahi)  (~16-bit mantissa total)
// ---------------------------------------------------------------------------
__global__ __launch_bounds__(256) void build_adj(const int* __restrict__ esrc,
                                                 const int* __restrict__ edst,
                                                 unsigned short* __restrict__ Ahi,
                                                 unsigned short* __restrict__ Alo)
{
    int g = blockIdx.x;
    __shared__ float A[4096];
    __shared__ int   cnt[64];
    __shared__ float dinv[64];
    int tid = threadIdx.x;
    for (int i = tid; i < 4096; i += 256) A[i] = 0.f;
    if (tid < 64) cnt[tid] = 0;
    __syncthreads();
    for (int e = tid; e < EPER; e += 256)
        atomicAdd(&cnt[edst[(size_t)g * EPER + e] & 63], 1);
    __syncthreads();
    if (tid < 64) dinv[tid] = rsqrtf((float)cnt[tid] + 1.0f);
    __syncthreads();
    for (int e = tid; e < EPER; e += 256) {
        int s = esrc[(size_t)g * EPER + e] & 63;
        int d = edst[(size_t)g * EPER + e] & 63;
        atomicAdd(&A[d * 64 + s], dinv[s] * dinv[d]);   // row-major [dst][src]
    }
    __syncthreads();
    if (tid < 64) A[tid * 64 + tid] += dinv[tid] * dinv[tid];
    __syncthreads();
    for (int i = tid; i < 4096; i += 256) {
        float v = A[i];
        unsigned short hi = f2b(v);
        Ahi[(size_t)g * 4096 + i] = hi;
        Alo[(size_t)g * 4096 + i] = f2b(v - b2f(hi));
    }
}

// ---------------------------------------------------------------------------
// triu(64, k=1) flat-offset table: off[t] = iu*64 + ju
// ---------------------------------------------------------------------------
__global__ void triu_off(int* __restrict__ off)
{
    int i = threadIdx.x;
    if (i >= 63) return;
    int o = 63 * i - i * (i - 1) / 2;
    for (int j = i + 1; j < 64; ++j) { off[o] = i * 64 + j; ++o; }
}

// ---------------------------------------------------------------------------
// fp32 x -> bf16 copy (layer-0 A operand, [16384][64])
// ---------------------------------------------------------------------------
__global__ __launch_bounds__(256) void conv_x(const float* __restrict__ x,
                                              unsigned short* __restrict__ Xbf)
{
    int i = (blockIdx.x * 256 + threadIdx.x) * 4;   // < 16384*64
    float4 v = *(const float4*)&x[i];
    Xbf[i + 0] = f2b(v.x); Xbf[i + 1] = f2b(v.y);
    Xbf[i + 2] = f2b(v.z); Xbf[i + 3] = f2b(v.w);
}

// ---------------------------------------------------------------------------
// Weight transpose+convert: Wt[n][k] = bf16(W[k][n]), zero-padded to [512][KP]
// ---------------------------------------------------------------------------
__global__ void convWt(const float* __restrict__ W, unsigned short* __restrict__ Wt,
                       int K, int N, int KP)
{
    __shared__ float T[32][33];
    int k0 = blockIdx.y * 32, n0 = blockIdx.x * 32;
    int tx = threadIdx.x, ty = threadIdx.y;
#pragma unroll
    for (int j = 0; j < 32; j += 8) {
        int k = k0 + ty + j, n = n0 + tx;
        T[ty + j][tx] = (k < K && n < N) ? W[(size_t)k * N + n] : 0.f;
    }
    __syncthreads();
#pragma unroll
    for (int j = 0; j < 32; j += 8) {
        int n = n0 + ty + j, k = k0 + tx;
        Wt[(size_t)n * KP + k] = f2b(T[tx][ty + j]);
    }
}

// ---------------------------------------------------------------------------
// bf16 MFMA feature GEMM: C = Abf[M][KP] @ Wt[512][KP]^T, written TRANSPOSED
// per graph as bf16: Xt[g][col(512)][row(64)].  KP in {64,512}.
// ---------------------------------------------------------------------------
__global__ __launch_bounds__(256) void gemm_mfma(const unsigned short* __restrict__ Abf,
                                                 const unsigned short* __restrict__ Wt,
                                                 unsigned short* __restrict__ Xt,
                                                 int KP)
{
    __shared__ unsigned short As[2][2048];   // [buf][r*32+k]
    __shared__ unsigned short Bs[2][2048];   // [buf][n*32+k]
    const int tid  = threadIdx.x;
    const int wave = tid >> 6, lane = tid & 63;
    const int g = blockIdx.y, col0 = blockIdx.x << 6;
    const int NT = KP >> 5;

    const int sr = tid >> 2;
    const int sk = (tid & 3) << 3;
    const unsigned short* gA = Abf + ((size_t)g * 64 + sr) * KP + sk;
    const unsigned short* gB = Wt  + (size_t)(col0 + sr) * KP + sk;

    int4 ra = *(const int4*)(const void*)gA;
    int4 rb = *(const int4*)(const void*)gB;
    *(int4*)(void*)&As[0][tid << 3] = ra;
    *(int4*)(void*)&Bs[0][tid << 3] = rb;
    __syncthreads();

    f32x4 acc0 = {0.f, 0.f, 0.f, 0.f};
    f32x4 acc1 = acc0, acc2 = acc0, acc3 = acc0;

    const int aoff = (wave * 16 + (lane & 15)) * 32 + ((lane >> 4) << 3);
    const int boff = (lane & 15) * 32 + ((lane >> 4) << 3);

    for (int t = 0; t < NT; ++t) {
        if (t + 1 < NT) {
            ra = *(const int4*)(const void*)(gA + (t + 1) * 32);
            rb = *(const int4*)(const void*)(gB + (t + 1) * 32);
        }
        const unsigned short* as = As[t & 1];
        const unsigned short* bs = Bs[t & 1];
        bfrag8 a  = *(const bfrag8*)(const void*)&as[aoff];
        bfrag8 b0 = *(const bfrag8*)(const void*)&bs[boff];
        bfrag8 b1 = *(const bfrag8*)(const void*)&bs[boff + 16 * 32];
        bfrag8 b2 = *(const bfrag8*)(const void*)&bs[boff + 32 * 32];
        bfrag8 b3 = *(const bfrag8*)(const void*)&bs[boff + 48 * 32];
        acc0 = __builtin_amdgcn_mfma_f32_16x16x32_bf16(a, b0, acc0, 0, 0, 0);
        acc1 = __builtin_amdgcn_mfma_f32_16x16x32_bf16(a, b1, acc1, 0, 0, 0);
        acc2 = __builtin_amdgcn_mfma_f32_16x16x32_bf16(a, b2, acc2, 0, 0, 0);
        acc3 = __builtin_amdgcn_mfma_f32_16x16x32_bf16(a, b3, acc3, 0, 0, 0);
        if (t + 1 < NT) {
            *(int4*)(void*)&As[(t + 1) & 1][tid << 3] = ra;
            *(int4*)(void*)&Bs[(t + 1) & 1][tid << 3] = rb;
        }
        __syncthreads();
    }

    unsigned short* Xg = Xt + (size_t)g * 32768;
    const int rloc = wave * 16 + ((lane >> 4) << 2);
    const int cb = col0 + (lane & 15);
    f32x4 accs[4] = {acc0, acc1, acc2, acc3};
#pragma unroll
    for (int j = 0; j < 4; ++j) {
        us4 p;
        p.a = f2b(accs[j][0]); p.b = f2b(accs[j][1]);
        p.c = f2b(accs[j][2]); p.d = f2b(accs[j][3]);
        *(us4*)(void*)&Xg[(cb + j * 16) * 64 + rloc] = p;
    }
}

// ---------------------------------------------------------------------------
// Adjacency GCN step (MFMA, split-bf16 A) + fused bias, bf16 store, pool.
// ---------------------------------------------------------------------------
__global__ __launch_bounds__(256) void adjmm_gcn(const unsigned short* __restrict__ Ahi,
                                                 const unsigned short* __restrict__ Alo,
                                                 const unsigned short* __restrict__ Xt,
                                                 const float* __restrict__ bias,
                                                 unsigned short* __restrict__ Ybf,
                                                 float* __restrict__ hs, int layer)
{
    const int g = blockIdx.y, c0 = blockIdx.x << 6;
    const int tid = threadIdx.x, w = tid >> 6, lane = tid & 63;
    const int lm = lane & 15, lh = lane >> 4;
    __shared__ float pb[4][64];

    const unsigned short* Ah = Ahi + (size_t)g * 4096;
    const unsigned short* Al = Alo + (size_t)g * 4096;
    const int arow = (w * 16 + lm) * 64 + (lh << 3);
    bfrag8 ah0 = *(const bfrag8*)(const void*)&Ah[arow];
    bfrag8 ah1 = *(const bfrag8*)(const void*)&Ah[arow + 32];
    bfrag8 al0 = *(const bfrag8*)(const void*)&Al[arow];
    bfrag8 al1 = *(const bfrag8*)(const void*)&Al[arow + 32];

    const unsigned short* Xg = Xt + (size_t)g * 32768;
    f32x4 acc[4];
#pragma unroll
    for (int nt = 0; nt < 4; ++nt) acc[nt] = (f32x4){0.f, 0.f, 0.f, 0.f};

#pragma unroll
    for (int nt = 0; nt < 4; ++nt) {
        const int col = c0 + nt * 16 + lm;
        bfrag8 b0 = *(const bfrag8*)(const void*)&Xg[col * 64 + (lh << 3)];
        bfrag8 b1 = *(const bfrag8*)(const void*)&Xg[col * 64 + 32 + (lh << 3)];
        acc[nt] = __builtin_amdgcn_mfma_f32_16x16x32_bf16(ah0, b0, acc[nt], 0, 0, 0);
        acc[nt] = __builtin_amdgcn_mfma_f32_16x16x32_bf16(al0, b0, acc[nt], 0, 0, 0);
        acc[nt] = __builtin_amdgcn_mfma_f32_16x16x32_bf16(ah1, b1, acc[nt], 0, 0, 0);
        acc[nt] = __builtin_amdgcn_mfma_f32_16x16x32_bf16(al1, b1, acc[nt], 0, 0, 0);
    }

    const int rbase = w * 16 + (lh << 2);
#pragma unroll
    for (int nt = 0; nt < 4; ++nt) {
        const int col = c0 + nt * 16 + lm;
        const float bv = (col < HC) ? bias[col] : 0.f;
#pragma unroll
        for (int r = 0; r < 4; ++r) {
            acc[nt][r] += bv;
            Ybf[((size_t)g * 64 + rbase + r) * 512 + col] = f2b(acc[nt][r]);
        }
        float cs = acc[nt][0] + acc[nt][1] + acc[nt][2] + acc[nt][3];
        cs += __shfl_xor(cs, 16, 64);
        cs += __shfl_xor(cs, 32, 64);
        if (lh == 0) pb[w][nt * 16 + lm] = cs;
    }
    __syncthreads();
    if (tid < 64) {
        int col = c0 + tid;
        if (col < HC) {
            float s = pb[0][tid] + pb[1][tid] + pb[2][tid] + pb[3][tid];
            hs[(size_t)g * (HC * NLAY) + layer * HC + col] = s * (1.0f / 64.0f);
        }
    }
}

// ---------------------------------------------------------------------------
// BN statistics, stage 1: partial sums over a row block (coalesced).
// grid (ceil(F/256), GB); each block sums rpb rows for 256 features.
// ---------------------------------------------------------------------------
__global__ __launch_bounds__(256) void stats_part(const float* __restrict__ in,
                                                  float* __restrict__ ps,
                                                  float* __restrict__ pss,
                                                  int F, int rpb)
{
    int f = blockIdx.x * 256 + threadIdx.x;
    if (f >= F) return;
    int r0 = blockIdx.y * rpb;
    float s = 0.f, ss = 0.f;
    for (int r = r0; r < r0 + rpb; ++r) {
        float v = in[(size_t)r * F + f];
        s += v; ss += v * v;
    }
    ps [(size_t)blockIdx.y * F + f] = s;
    pss[(size_t)blockIdx.y * F + f] = ss;
}

// ---------------------------------------------------------------------------
// BN statistics, stage 2: reduce GB partials -> mean, rsqrt(var+eps)
// ---------------------------------------------------------------------------
__global__ __launch_bounds__(256) void stats_fin(const float* __restrict__ ps,
                                                 const float* __restrict__ pss,
                                                 float* __restrict__ mean,
                                                 float* __restrict__ inv,
                                                 int F, int GB, float invR)
{
    int f = blockIdx.x * 256 + threadIdx.x;
    if (f >= F) return;
    float s = 0.f, ss = 0.f;
    for (int b = 0; b < GB; ++b) { s += ps[(size_t)b * F + f]; ss += pss[(size_t)b * F + f]; }
    float m = s * invR;
    mean[f] = m;
    inv[f]  = rsqrtf(ss * invR - m * m + 1e-5f);
}

// ---------------------------------------------------------------------------
// Gather triu entries of x into xv[g][t] + partial stats over 16 graphs.
// grid (8, 16).
// ---------------------------------------------------------------------------
__global__ __launch_bounds__(256) void xv_gather(const float* __restrict__ x,
                                                 const int* __restrict__ off,
                                                 float* __restrict__ xv,
                                                 float* __restrict__ ps,
                                                 float* __restrict__ pss)
{
    int t = blockIdx.x * 256 + threadIdx.x;
    if (t >= NTRIU) return;
    int o = off[t];
    int g0 = blockIdx.y * 16;
    float s = 0.f, ss = 0.f;
    for (int g = g0; g < g0 + 16; ++g) {
        float v = x[(size_t)g * 4096 + o];
        xv[(size_t)g * NTRIU + t] = v;
        s += v; ss += v * v;
    }
    ps [(size_t)blockIdx.y * NTRIU + t] = s;
    pss[(size_t)blockIdx.y * NTRIU + t] = ss;
}

// ---------------------------------------------------------------------------
// Fused: normalize xv & hs inline, attention dot, sigmoid, write z.
// One block per graph.
// ---------------------------------------------------------------------------
__global__ __launch_bounds__(256) void attz_fused(const float* __restrict__ xv,
                                                  const float* __restrict__ xm,
                                                  const float* __restrict__ xi,
                                                  const float* __restrict__ gx,
                                                  const float* __restrict__ bx,
                                                  const float* __restrict__ hsrc,
                                                  const float* __restrict__ hm,
                                                  const float* __restrict__ hi,
                                                  const float* __restrict__ gh,
                                                  const float* __restrict__ bh,
                                                  const float* __restrict__ Watt,
                                                  const float* __restrict__ batt,
                                                  float* __restrict__ z)
{
    int g = blockIdx.x;
    __shared__ float xs[NTRIU];
    __shared__ float red[256];
    float s = 0.f;
    for (int t = threadIdx.x; t < NTRIU; t += 256) {
        float v = (xv[(size_t)g * NTRIU + t] - xm[t]) * xi[t] * gx[t] + bx[t];
        xs[t] = v;
        s += v * Watt[t];
    }
    red[threadIdx.x] = s;
    __syncthreads();
    for (int w = 128; w > 0; w >>= 1) {
        if (threadIdx.x < w) red[threadIdx.x] += red[threadIdx.x + w];
        __syncthreads();
    }
    float att = 1.0f / (1.0f + expf(-(red[0] + batt[0])));
    for (int t = threadIdx.x; t < NTRIU; t += 256) {
        float hn = (hsrc[(size_t)g * NTRIU + t] - hm[t]) * hi[t] * gh[t] + bh[t];
        z[(size_t)g * DCAT + t]         = att * xs[t] + (1.0f - att) * hn * 0.5f;
        z[(size_t)g * DCAT + NTRIU + t] = hn;
    }
}

// ---------------------------------------------------------------------------
// Elementwise BN apply + ReLU (in place). F power of two (mask = F-1).
// ---------------------------------------------------------------------------
__global__ __launch_bounds__(256) void bn_apply(float* __restrict__ buf,
                                                const float* __restrict__ mean,
                                                const float* __restrict__ inv,
                                                const float* __restrict__ gamma,
                                                const float* __restrict__ beta,
                                                int total, int mask)
{
    int i = blockIdx.x * 256 + threadIdx.x;
    if (i >= total) return;
    int f = i & mask;
    float v = (buf[i] - mean[f]) * inv[f] * gamma[f] + beta[f];
    buf[i] = fmaxf(v, 0.f);
}

// ---------------------------------------------------------------------------
// Split-K fp32 SGEMM: P[s][M][N] partial = A[M, kb..kb+chunk] @ B[.., N]
// ---------------------------------------------------------------------------
__global__ __launch_bounds__(256) void sgemm_sk(const float* __restrict__ A,
                                                const float* __restrict__ B,
                                                float* __restrict__ P,
                                                int M, int N, int K, int chunk)
{
    __shared__ float As[16][68];
    __shared__ float Bs[16][68];
    const int tid = threadIdx.x;
    const int tx = tid & 15, ty = tid >> 4;
    const int row0 = blockIdx.y << 6;
    const int col0 = blockIdx.x << 6;
    const int kb = blockIdx.z * chunk;
    const int ar  = tid >> 2;
    const int aq  = (tid & 3) << 2;
    const int bk  = tid >> 4;
    const int bn4 = (tid & 15) << 2;
    float acc[4][4] = {};
    for (int k0 = 0; k0 < chunk; k0 += 16) {
        float4 a4 = *(const float4*)&A[(size_t)(row0 + ar) * K + kb + k0 + aq];
        As[aq + 0][ar] = a4.x; As[aq + 1][ar] = a4.y;
        As[aq + 2][ar] = a4.z; As[aq + 3][ar] = a4.w;
        *(float4*)&Bs[bk][bn4] = *(const float4*)&B[(size_t)(kb + k0 + bk) * N + col0 + bn4];
        __syncthreads();
#pragma unroll
        for (int kk = 0; kk < 16; ++kk) {
            float4 a = *(const float4*)&As[kk][ty << 2];
            float4 b = *(const float4*)&Bs[kk][tx << 2];
            float av[4] = {a.x, a.y, a.z, a.w};
            float bv[4] = {b.x, b.y, b.z, b.w};
#pragma unroll
            for (int i = 0; i < 4; ++i)
#pragma unroll
                for (int j = 0; j < 4; ++j)
                    acc[i][j] += av[i] * bv[j];
        }
        __syncthreads();
    }
    float* Pp = P + (size_t)blockIdx.z * M * N;
#pragma unroll
    for (int i = 0; i < 4; ++i) {
        int r = row0 + (ty << 2) + i;
#pragma unroll
        for (int j = 0; j < 4; ++j)
            Pp[(size_t)r * N + col0 + (tx << 2) + j] = acc[i][j];
    }
}

// ---------------------------------------------------------------------------
// Sum S split-K partials + bias. Nmask = N-1 (N power of two).
// ---------------------------------------------------------------------------
__global__ void reduce_add(const float* __restrict__ P, const float* __restrict__ bias,
                           float* __restrict__ C, int MN, int Nmask, int S)
{
    int i = blockIdx.x * 256 + threadIdx.x;
    if (i >= MN) return;
    float s = 0.f;
    for (int t = 0; t < S; ++t) s += P[(size_t)t * MN + i];
    C[i] = s + bias[i & Nmask];
}

// ---------------------------------------------------------------------------
// Final tiny linear: out[g][0:2] = m3[g] @ Wm4 + bm4
// ---------------------------------------------------------------------------
__global__ __launch_bounds__(256) void final_kernel(const float* __restrict__ X,
                                                    const float* __restrict__ W,
                                                    const float* __restrict__ b,
                                                    float* __restrict__ out)
{
    int g = blockIdx.x;
    float s0 = 0.f, s1 = 0.f;
    for (int k = threadIdx.x; k < HID2; k += 256) {
        float v = X[(size_t)g * HID2 + k];
        s0 += v * W[k * 2 + 0];
        s1 += v * W[k * 2 + 1];
    }
    __shared__ float r0[256], r1[256];
    r0[threadIdx.x] = s0; r1[threadIdx.x] = s1;
    __syncthreads();
    for (int w = 128; w > 0; w >>= 1) {
        if (threadIdx.x < w) {
            r0[threadIdx.x] += r0[threadIdx.x + w];
            r1[threadIdx.x] += r1[threadIdx.x + w];
        }
        __syncthreads();
    }
    if (threadIdx.x == 0) {
        out[g * 2 + 0] = r0[0] + b[0];
        out[g * 2 + 1] = r1[0] + b[1];
    }
}

// ---------------------------------------------------------------------------
extern "C" void kernel_launch(void* const* d_in, const int* in_sizes, int n_in,
                              void* d_out, int out_size, void* d_ws, size_t ws_size,
                              hipStream_t stream)
{
    const float* x      = (const float*)d_in[0];
    const float* Wg0    = (const float*)d_in[1];
    const float* bg0    = (const float*)d_in[2];
    const float* WgR    = (const float*)d_in[3];
    const float* bgR    = (const float*)d_in[4];
    const float* gx     = (const float*)d_in[5];
    const float* bx     = (const float*)d_in[6];
    const float* gh     = (const float*)d_in[7];
    const float* bh     = (const float*)d_in[8];
    const float* Watt   = (const float*)d_in[9];
    const float* batt   = (const float*)d_in[10];
    const float* Wm1    = (const float*)d_in[11];
    const float* bm1    = (const float*)d_in[12];
    const float* gm1    = (const float*)d_in[13];
    const float* bem1   = (const float*)d_in[14];
    const float* Wm2    = (const float*)d_in[15];
    const float* bm2    = (const float*)d_in[16];
    const float* gm2    = (const float*)d_in[17];
    const float* bem2   = (const float*)d_in[18];
    const float* Wm3    = (const float*)d_in[19];
    const float* bm3    = (const float*)d_in[20];
    const float* gm3    = (const float*)d_in[21];
    const float* bem3   = (const float*)d_in[22];
    const float* Wm4    = (const float*)d_in[23];
    const float* bm4    = (const float*)d_in[24];
    const int*   esrc   = (const int*)d_in[25];
    const int*   edst   = (const int*)d_in[26];
    float* out = (float*)d_out;

    char* w = (char*)d_ws;
    auto alloc = [&](size_t bytes) -> char* {
        char* p = w;
        w += (bytes + 255) & ~(size_t)255;
        return p;
    };
    unsigned short* Ahi  = (unsigned short*)alloc((size_t)NGRAPH * 4096 * 2);
    unsigned short* Alo  = (unsigned short*)alloc((size_t)NGRAPH * 4096 * 2);
    unsigned short* Xt   = (unsigned short*)alloc((size_t)NGRAPH * 32768 * 2); // 16.8MB
    unsigned short* Ybf  = (unsigned short*)alloc((size_t)16384 * 512 * 2);
    unsigned short* Xbf  = (unsigned short*)alloc((size_t)16384 * 64 * 2);
    unsigned short* Wt0  = (unsigned short*)alloc((size_t)512 * 64 * 2);
    unsigned short* Wt1  = (unsigned short*)alloc((size_t)512 * 512 * 2);
    unsigned short* Wt2  = (unsigned short*)alloc((size_t)512 * 512 * 2);
    unsigned short* Wt3  = (unsigned short*)alloc((size_t)512 * 512 * 2);
    float*          hs   = (float*)alloc((size_t)NGRAPH * NTRIU * 4);
    float*          xv   = (float*)alloc((size_t)NGRAPH * NTRIU * 4);
    float*          z    = (float*)alloc((size_t)NGRAPH * DCAT * 4);
    float*          m1   = (float*)alloc((size_t)NGRAPH * HID1 * 4);
    float*          m2   = (float*)alloc((size_t)NGRAPH * HID2 * 4);
    float*          m3   = (float*)alloc((size_t)NGRAPH * HID2 * 4);
    float*          ps   = (float*)alloc((size_t)16 * NTRIU * 4);
    float*          pss  = (float*)alloc((size_t)16 * NTRIU * 4);
    float*          xm   = (float*)alloc(NTRIU * 4);
    float*          xi   = (float*)alloc(NTRIU * 4);
    float*          hm   = (float*)alloc(NTRIU * 4);
    float*          hi   = (float*)alloc(NTRIU * 4);
    float*          mmean = (float*)alloc(HID1 * 4);
    float*          minv  = (float*)alloc(HID1 * 4);
    int*            off  = (int*)alloc(NTRIU * 4);
    float*          P    = (float*)Xt;   // split-K partials reuse Xt (dead after GCN)

    build_adj<<<NGRAPH, 256, 0, stream>>>(esrc, edst, Ahi, Alo);
    triu_off<<<1, 64, 0, stream>>>(off);
    conv_x<<<1024, 256, 0, stream>>>(x, Xbf);
    convWt<<<dim3(16, 2),  dim3(32, 8), 0, stream>>>(Wg0, Wt0, 64, HC, 64);
    convWt<<<dim3(16, 16), dim3(32, 8), 0, stream>>>(WgR + 0 * HC * HC, Wt1, HC, HC, 512);
    convWt<<<dim3(16, 16), dim3(32, 8), 0, stream>>>(WgR + 1 * HC * HC, Wt2, HC, HC, 512);
    convWt<<<dim3(16, 16), dim3(32, 8), 0, stream>>>(WgR + 2 * HC * HC, Wt3, HC, HC, 512);

    // GCN layers: Xt = (cur @ W)^T bf16 (mfma), then adjacency+pool (mfma)
    gemm_mfma<<<dim3(8, 256), 256, 0, stream>>>(Xbf, Wt0, Xt, 64);
    adjmm_gcn<<<dim3(8, 256), 256, 0, stream>>>(Ahi, Alo, Xt, bg0, Ybf, hs, 0);
    const unsigned short* Wts[3] = {Wt1, Wt2, Wt3};
    for (int l = 1; l < NLAY; ++l) {
        gemm_mfma<<<dim3(8, 256), 256, 0, stream>>>(Ybf, Wts[l - 1], Xt, 512);
        adjmm_gcn<<<dim3(8, 256), 256, 0, stream>>>(Ahi, Alo, Xt, bgR + (l - 1) * HC, Ybf, hs, l);
    }

    // BN stats for h (from hs) and xv (gather + stats), then fused att+z
    stats_part<<<dim3(8, 16), 256, 0, stream>>>(hs, ps, pss, NTRIU, 16);
    stats_fin<<<8, 256, 0, stream>>>(ps, pss, hm, hi, NTRIU, 16, 1.0f / NGRAPH);
    xv_gather<<<dim3(8, 16), 256, 0, stream>>>(x, off, xv, ps, pss);
    stats_fin<<<8, 256, 0, stream>>>(ps, pss, xm, xi, NTRIU, 16, 1.0f / NGRAPH);
    attz_fused<<<NGRAPH, 256, 0, stream>>>(xv, xm, xi, gx, bx, hs, hm, hi, gh, bh,
                                           Watt, batt, z);

    // MLP with split-K fp32 (P reuses Xt: 12*256*1024*4 = 12.6MB < 16.8MB)
    sgemm_sk<<<dim3(16, 4, 12), 256, 0, stream>>>(z, Wm1, P, NGRAPH, HID1, DCAT, 336);
    reduce_add<<<1024, 256, 0, stream>>>(P, bm1, m1, NGRAPH * HID1, HID1 - 1, 12);
    stats_part<<<dim3(4, 16), 256, 0, stream>>>(m1, ps, pss, HID1, 16);
    stats_fin<<<4, 256, 0, stream>>>(ps, pss, mmean, minv, HID1, 16, 1.0f / NGRAPH);
    bn_apply<<<1024, 256, 0, stream>>>(m1, mmean, minv, gm1, bem1, NGRAPH * HID1, HID1 - 1);

    sgemm_sk<<<dim3(8, 4, 8), 256, 0, stream>>>(m1, Wm2, P, NGRAPH, HID2, HID1, 128);
    reduce_add<<<512, 256, 0, stream>>>(P, bm2, m2, NGRAPH * HID2, HID2 - 1, 8);
    stats_part<<<dim3(2, 16), 256, 0, stream>>>(m2, ps, pss, HID2, 16);
    stats_fin<<<2, 256, 0, stream>>>(ps, pss, mmean, minv, HID2, 16, 1.0f / NGRAPH);
    bn_apply<<<512, 256, 0, stream>>>(m2, mmean, minv, gm2, bem2, NGRAPH * HID2, HID2 - 1);

    sgemm_sk<<<dim3(8, 4, 8), 256, 0, stream>>>(m2, Wm3, P, NGRAPH, HID2, HID2, 64);
    reduce_add<<<512, 256, 0, stream>>>(P, bm3, m3, NGRAPH * HID2, HID2 - 1, 8);
    stats_part<<<dim3(2, 16), 256, 0, stream>>>(m3, ps, pss, HID2, 16);
    stats_fin<<<2, 256, 0, stream>>>(ps, pss, mmean, minv, HID2, 16, 1.0f / NGRAPH);
    bn_apply<<<512, 256, 0, stream>>>(m3, mmean, minv, gm3, bem3, NGRAPH * HID2, HID2 - 1);

    final_kernel<<<NGRAPH, 256, 0, stream>>>(m3, Wm4, bm4, out);
}

// Round 5
// 314.691 us; speedup vs baseline: 8.9572x; 1.0027x over previous
//
#include <hip/hip_runtime.h>
#include <math.h>

#define NGRAPH 256
#define NPG 64
#define NFEAT 64
#define HC 504
#define NLAY 4
#define EPER 1024
#define NTRIU 2016
#define DCAT 4032
#define HID1 1024
#define HID2 512

#define GCN_LDS (65536 + 73728 + 16384)   // cur + xwt + ahl = 155648 B

typedef __attribute__((ext_vector_type(8))) short bfrag8;   // 8 bf16 in 4 VGPRs
typedef __attribute__((ext_vector_type(4))) float f32x4;

struct __align__(8) us4 { unsigned short a, b, c, d; };

__device__ __forceinline__ unsigned short f2b(float f) {
    union { float f; unsigned u; } v; v.f = f;
    unsigned r = (v.u + 0x7fffu + ((v.u >> 16) & 1u)) >> 16;   // RNE
    return (unsigned short)r;
}
__device__ __forceinline__ float b2f(unsigned short h) {
    union { unsigned u; float f; } v; v.u = ((unsigned)h) << 16;
    return v.f;
}

// ---------------------------------------------------------------------------
// triu(64, k=1) flat-offset table: off[t] = iu*64 + ju
// ---------------------------------------------------------------------------
__global__ void triu_off(int* __restrict__ off)
{
    int i = threadIdx.x;
    if (i >= 63) return;
    int o = 63 * i - i * (i - 1) / 2;
    for (int j = i + 1; j < 64; ++j) { off[o] = i * 64 + j; ++o; }
}

// ---------------------------------------------------------------------------
// Weight transpose+convert: Wt[n][k] = bf16(W[k][n]); zero-pad K/N to grid
// coverage. blockIdx.z batches tensors (sStride/dStride element strides).
// ---------------------------------------------------------------------------
__global__ void convWt(const float* __restrict__ W, unsigned short* __restrict__ Wt,
                       int K, int N, int KP, long long sStride, long long dStride)
{
    W  += (size_t)blockIdx.z * sStride;
    Wt += (size_t)blockIdx.z * dStride;
    __shared__ float T[32][33];
    int k0 = blockIdx.y * 32, n0 = blockIdx.x * 32;
    int tx = threadIdx.x, ty = threadIdx.y;
#pragma unroll
    for (int j = 0; j < 32; j += 8) {
        int k = k0 + ty + j, n = n0 + tx;
        T[ty + j][tx] = (k < K && n < N) ? W[(size_t)k * N + n] : 0.f;
    }
    __syncthreads();
#pragma unroll
    for (int j = 0; j < 32; j += 8) {
        int n = n0 + ty + j, k = k0 + tx;
        Wt[(size_t)n * KP + k] = f2b(T[tx][ty + j]);
    }
}

// ---------------------------------------------------------------------------
// Whole-GCN mega-kernel: one block = one graph, all 4 layers in LDS.
//   cur [64][512] bf16 (k XOR-swizzled by ((row&7)<<3))
//   xwt [512][72] bf16 (XW transposed: xwt[c][m])
//   ahl [2][4096] bf16 (split hi/lo adjacency, row-major [dst][src])
// Per layer: XW = cur @ Wt^T (MFMA, weights from L2), Y = A@XW + bias
// (MFMA, hi/lo), fused mean-pool -> hs, Y -> cur (bf16).
// ---------------------------------------------------------------------------
__global__ __launch_bounds__(256, 1) void gcn_all(const float* __restrict__ x,
                                                  const int* __restrict__ esrc,
                                                  const int* __restrict__ edst,
                                                  const unsigned short* __restrict__ Wt0,
                                                  const unsigned short* __restrict__ Wt123,
                                                  const float* __restrict__ bg0,
                                                  const float* __restrict__ bgR,
                                                  float* __restrict__ hs)
{
    extern __shared__ char lds[];
    unsigned short* cur = (unsigned short*)lds;                    // 65536 B
    unsigned short* xwt = (unsigned short*)(lds + 65536);          // 73728 B
    unsigned short* ahl = (unsigned short*)(lds + 65536 + 73728);  // 16384 B
    float* Af   = (float*)(lds + 65536);                           // scratch in xwt
    int*   cnt  = (int*)(lds + 65536 + 16384);
    float* dinv = (float*)(lds + 65536 + 16384 + 256);

    const int g = blockIdx.x, tid = threadIdx.x;
    const int wv = tid >> 6, lane = tid & 63;
    const int lm = lane & 15, lh = lane >> 4;

    // ---- build normalized adjacency in LDS ----
    for (int i = tid; i < 4096; i += 256) Af[i] = 0.f;
    if (tid < 64) cnt[tid] = 0;
    __syncthreads();
    for (int e = tid; e < EPER; e += 256)
        atomicAdd(&cnt[edst[(size_t)g * EPER + e] & 63], 1);
    __syncthreads();
    if (tid < 64) dinv[tid] = rsqrtf((float)cnt[tid] + 1.0f);
    __syncthreads();
    for (int e = tid; e < EPER; e += 256) {
        int s = esrc[(size_t)g * EPER + e] & 63;
        int d = edst[(size_t)g * EPER + e] & 63;
        atomicAdd(&Af[d * 64 + s], dinv[s] * dinv[d]);
    }
    __syncthreads();
    if (tid < 64) Af[tid * 64 + tid] += dinv[tid] * dinv[tid];
    __syncthreads();
    for (int i = tid; i < 4096; i += 256) {
        float v = Af[i];
        unsigned short h = f2b(v);
        ahl[i] = h;
        ahl[4096 + i] = f2b(v - b2f(h));
    }
    // ---- load x -> cur (bf16, swizzled); layer0 uses k<64 only ----
    for (int i = tid; i < 1024; i += 256) {
        float4 v = ((const float4*)(x + (size_t)g * 4096))[i];
        int row = (i * 4) >> 6, col = (i * 4) & 63;
        unsigned short* p = &cur[row * 512 + (col ^ ((row & 7) << 3))];
        p[0] = f2b(v.x); p[1] = f2b(v.y); p[2] = f2b(v.z); p[3] = f2b(v.w);
    }
    __syncthreads();

    // ---- adjacency fragments held in registers for all layers ----
    bfrag8 ah[4][2], al[4][2];
#pragma unroll
    for (int m0 = 0; m0 < 4; ++m0)
#pragma unroll
        for (int kc = 0; kc < 2; ++kc) {
            int o = (m0 * 16 + lm) * 64 + kc * 32 + (lh << 3);
            ah[m0][kc] = *(const bfrag8*)(const void*)&ahl[o];
            al[m0][kc] = *(const bfrag8*)(const void*)&ahl[4096 + o];
        }

    const int colw = wv * 128;
    const int kswz = (lm & 7) << 3;

    for (int l = 0; l < NLAY; ++l) {
        const unsigned short* Wt = (l == 0) ? Wt0 : Wt123 + (size_t)(l - 1) * 512 * 512;
        const float* bias = (l == 0) ? bg0 : bgR + (l - 1) * HC;
        const int KL = (l == 0) ? 64 : 512;

        // ---- feature GEMM: XW = cur @ Wt^T ----
        f32x4 acc[4][8];
#pragma unroll
        for (int m0 = 0; m0 < 4; ++m0)
#pragma unroll
            for (int cc = 0; cc < 8; ++cc) acc[m0][cc] = (f32x4){0.f, 0.f, 0.f, 0.f};
        for (int kt = 0; kt < (KL >> 5); ++kt) {
            const int kb2 = kt * 32 + (lh << 3);
            bfrag8 a[4];
#pragma unroll
            for (int m0 = 0; m0 < 4; ++m0)
                a[m0] = *(const bfrag8*)(const void*)&cur[(m0 * 16 + lm) * 512 + (kb2 ^ kswz)];
#pragma unroll
            for (int cc = 0; cc < 8; ++cc) {
                const int c = colw + cc * 16 + lm;
                bfrag8 b = *(const bfrag8*)(const void*)&Wt[(size_t)c * KL + kb2];
#pragma unroll
                for (int m0 = 0; m0 < 4; ++m0)
                    acc[m0][cc] = __builtin_amdgcn_mfma_f32_16x16x32_bf16(a[m0], b, acc[m0][cc], 0, 0, 0);
            }
        }
        // ---- write XW transposed (bf16) to xwt[c][m] ----
#pragma unroll
        for (int cc = 0; cc < 8; ++cc) {
            const int c = colw + cc * 16 + lm;
#pragma unroll
            for (int m0 = 0; m0 < 4; ++m0) {
                const int rloc = m0 * 16 + (lh << 2);
                us4 p;
                p.a = f2b(acc[m0][cc][0]); p.b = f2b(acc[m0][cc][1]);
                p.c = f2b(acc[m0][cc][2]); p.d = f2b(acc[m0][cc][3]);
                *(us4*)(void*)&xwt[c * 72 + rloc] = p;
            }
        }
        __syncthreads();   // all cur reads + own xwt writes complete

        // ---- adjacency: Y = A @ XW (hi/lo split) ----
#pragma unroll
        for (int m0 = 0; m0 < 4; ++m0)
#pragma unroll
            for (int cc = 0; cc < 8; ++cc) acc[m0][cc] = (f32x4){0.f, 0.f, 0.f, 0.f};
#pragma unroll
        for (int cc = 0; cc < 8; ++cc) {
            const int c = colw + cc * 16 + lm;
            bfrag8 b0 = *(const bfrag8*)(const void*)&xwt[c * 72 + (lh << 3)];
            bfrag8 b1 = *(const bfrag8*)(const void*)&xwt[c * 72 + 32 + (lh << 3)];
#pragma unroll
            for (int m0 = 0; m0 < 4; ++m0) {
                acc[m0][cc] = __builtin_amdgcn_mfma_f32_16x16x32_bf16(ah[m0][0], b0, acc[m0][cc], 0, 0, 0);
                acc[m0][cc] = __builtin_amdgcn_mfma_f32_16x16x32_bf16(al[m0][0], b0, acc[m0][cc], 0, 0, 0);
                acc[m0][cc] = __builtin_amdgcn_mfma_f32_16x16x32_bf16(ah[m0][1], b1, acc[m0][cc], 0, 0, 0);
                acc[m0][cc] = __builtin_amdgcn_mfma_f32_16x16x32_bf16(al[m0][1], b1, acc[m0][cc], 0, 0, 0);
            }
        }
        // ---- bias + pool + Y -> cur (bf16) ----
#pragma unroll
        for (int cc = 0; cc < 8; ++cc) {
            const int c = colw + cc * 16 + lm;
            const float bv = (c < HC) ? bias[c] : 0.f;
            float cs = 0.f;
#pragma unroll
            for (int m0 = 0; m0 < 4; ++m0) {
                const int rb_ = m0 * 16 + (lh << 2);
#pragma unroll
                for (int r = 0; r < 4; ++r) {
                    float v = acc[m0][cc][r] + bv;
                    cs += v;
                    const int row = rb_ + r;
                    cur[row * 512 + (c ^ ((row & 7) << 3))] = f2b(v);
                }
            }
            cs += __shfl_xor(cs, 16, 64);
            cs += __shfl_xor(cs, 32, 64);
            if (lh == 0 && c < HC)
                hs[(size_t)g * (HC * NLAY) + l * HC + c] = cs * (1.0f / 64.0f);
        }
        __syncthreads();   // cur writes complete before next layer reads
    }
}

// ---------------------------------------------------------------------------
// BN statistics, stage 1: partial sums over a row block (coalesced).
// ---------------------------------------------------------------------------
__global__ __launch_bounds__(256) void stats_part(const float* __restrict__ in,
                                                  float* __restrict__ ps,
                                                  float* __restrict__ pss,
                                                  int F, int rpb)
{
    int f = blockIdx.x * 256 + threadIdx.x;
    if (f >= F) return;
    int r0 = blockIdx.y * rpb;
    float s = 0.f, ss = 0.f;
    for (int r = r0; r < r0 + rpb; ++r) {
        float v = in[(size_t)r * F + f];
        s += v; ss += v * v;
    }
    ps [(size_t)blockIdx.y * F + f] = s;
    pss[(size_t)blockIdx.y * F + f] = ss;
}

// ---------------------------------------------------------------------------
// BN statistics, stage 2: reduce GB partials -> mean, rsqrt(var+eps)
// ---------------------------------------------------------------------------
__global__ __launch_bounds__(256) void stats_fin(const float* __restrict__ ps,
                                                 const float* __restrict__ pss,
                                                 float* __restrict__ mean,
                                                 float* __restrict__ inv,
                                                 int F, int GB, float invR)
{
    int f = blockIdx.x * 256 + threadIdx.x;
    if (f >= F) return;
    float s = 0.f, ss = 0.f;
    for (int b = 0; b < GB; ++b) { s += ps[(size_t)b * F + f]; ss += pss[(size_t)b * F + f]; }
    float m = s * invR;
    mean[f] = m;
    inv[f]  = rsqrtf(ss * invR - m * m + 1e-5f);
}

// ---------------------------------------------------------------------------
// Gather triu entries of x into xv[g][t] + partial stats over 16 graphs.
// ---------------------------------------------------------------------------
__global__ __launch_bounds__(256) void xv_gather(const float* __restrict__ x,
                                                 const int* __restrict__ off,
                                                 float* __restrict__ xv,
                                                 float* __restrict__ ps,
                                                 float* __restrict__ pss)
{
    int t = blockIdx.x * 256 + threadIdx.x;
    if (t >= NTRIU) return;
    int o = off[t];
    int g0 = blockIdx.y * 16;
    float s = 0.f, ss = 0.f;
    for (int g = g0; g < g0 + 16; ++g) {
        float v = x[(size_t)g * 4096 + o];
        xv[(size_t)g * NTRIU + t] = v;
        s += v; ss += v * v;
    }
    ps [(size_t)blockIdx.y * NTRIU + t] = s;
    pss[(size_t)blockIdx.y * NTRIU + t] = ss;
}

// ---------------------------------------------------------------------------
// Fused: normalize xv & hs inline, attention dot, sigmoid, write z as
// split-bf16 (hi/lo) planes. One block per graph.
// ---------------------------------------------------------------------------
__global__ __launch_bounds__(256) void attz_fused(const float* __restrict__ xv,
                                                  const float* __restrict__ xm,
                                                  const float* __restrict__ xi,
                                                  const float* __restrict__ gx,
                                                  const float* __restrict__ bx,
                                                  const float* __restrict__ hsrc,
                                                  const float* __restrict__ hm,
                                                  const float* __restrict__ hi,
                                                  const float* __restrict__ gh,
                                                  const float* __restrict__ bh,
                                                  const float* __restrict__ Watt,
                                                  const float* __restrict__ batt,
                                                  unsigned short* __restrict__ zhi,
                                                  unsigned short* __restrict__ zlo)
{
    int g = blockIdx.x;
    __shared__ float xs[NTRIU];
    __shared__ float red[256];
    float s = 0.f;
    for (int t = threadIdx.x; t < NTRIU; t += 256) {
        float v = (xv[(size_t)g * NTRIU + t] - xm[t]) * xi[t] * gx[t] + bx[t];
        xs[t] = v;
        s += v * Watt[t];
    }
    red[threadIdx.x] = s;
    __syncthreads();
    for (int w = 128; w > 0; w >>= 1) {
        if (threadIdx.x < w) red[threadIdx.x] += red[threadIdx.x + w];
        __syncthreads();
    }
    float att = 1.0f / (1.0f + expf(-(red[0] + batt[0])));
    for (int t = threadIdx.x; t < NTRIU; t += 256) {
        float hn = (hsrc[(size_t)g * NTRIU + t] - hm[t]) * hi[t] * gh[t] + bh[t];
        float zf = att * xs[t] + (1.0f - att) * hn * 0.5f;
        unsigned short h0 = f2b(zf);
        zhi[(size_t)g * DCAT + t] = h0;
        zlo[(size_t)g * DCAT + t] = f2b(zf - b2f(h0));
        unsigned short h1 = f2b(hn);
        zhi[(size_t)g * DCAT + NTRIU + t] = h1;
        zlo[(size_t)g * DCAT + NTRIU + t] = f2b(hn - b2f(h1));
    }
}

// ---------------------------------------------------------------------------
// Split-K bf16 MFMA GEMM with hi/lo-split A:
// P[z][256][N] partial = (Ahi+Alo)[256][K-chunk] @ Bt[N][K]^T
// grid (N/64, 4, S); 64x64 tile; double-buffered LDS; chunk % 32 == 0.
// ---------------------------------------------------------------------------
__global__ __launch_bounds__(256) void gemm_bf_sk(const unsigned short* __restrict__ Ahi,
                                                  const unsigned short* __restrict__ Alo,
                                                  const unsigned short* __restrict__ Bt,
                                                  float* __restrict__ P,
                                                  int N, int K, int chunk)
{
    __shared__ unsigned short Ah[2][2048], Al[2][2048], Bs[2][2048];
    const int tid  = threadIdx.x;
    const int wave = tid >> 6, lane = tid & 63;
    const int row0 = blockIdx.y << 6, col0 = blockIdx.x << 6;
    const int kb = blockIdx.z * chunk;
    const int NT = chunk >> 5;
    const int sr = tid >> 2, sk = (tid & 3) << 3;
    const unsigned short* gAh = Ahi + (size_t)(row0 + sr) * K + kb + sk;
    const unsigned short* gAl = Alo + (size_t)(row0 + sr) * K + kb + sk;
    const unsigned short* gB  = Bt  + (size_t)(col0 + sr) * K + kb + sk;

    int4 rh = *(const int4*)(const void*)gAh;
    int4 rl = *(const int4*)(const void*)gAl;
    int4 rb = *(const int4*)(const void*)gB;
    *(int4*)(void*)&Ah[0][tid << 3] = rh;
    *(int4*)(void*)&Al[0][tid << 3] = rl;
    *(int4*)(void*)&Bs[0][tid << 3] = rb;
    __syncthreads();

    f32x4 acc0 = {0.f, 0.f, 0.f, 0.f};
    f32x4 acc1 = acc0, acc2 = acc0, acc3 = acc0;
    const int aoff = (wave * 16 + (lane & 15)) * 32 + ((lane >> 4) << 3);
    const int boff = (lane & 15) * 32 + ((lane >> 4) << 3);

    for (int t = 0; t < NT; ++t) {
        if (t + 1 < NT) {
            rh = *(const int4*)(const void*)(gAh + (t + 1) * 32);
            rl = *(const int4*)(const void*)(gAl + (t + 1) * 32);
            rb = *(const int4*)(const void*)(gB  + (t + 1) * 32);
        }
        const unsigned short* ah = Ah[t & 1];
        const unsigned short* al = Al[t & 1];
        const unsigned short* bs = Bs[t & 1];
        bfrag8 a  = *(const bfrag8*)(const void*)&ah[aoff];
        bfrag8 a2 = *(const bfrag8*)(const void*)&al[aoff];
        bfrag8 b0 = *(const bfrag8*)(const void*)&bs[boff];
        bfrag8 b1 = *(const bfrag8*)(const void*)&bs[boff + 16 * 32];
        bfrag8 b2 = *(const bfrag8*)(const void*)&bs[boff + 32 * 32];
        bfrag8 b3 = *(const bfrag8*)(const void*)&bs[boff + 48 * 32];
        acc0 = __builtin_amdgcn_mfma_f32_16x16x32_bf16(a,  b0, acc0, 0, 0, 0);
        acc0 = __builtin_amdgcn_mfma_f32_16x16x32_bf16(a2, b0, acc0, 0, 0, 0);
        acc1 = __builtin_amdgcn_mfma_f32_16x16x32_bf16(a,  b1, acc1, 0, 0, 0);
        acc1 = __builtin_amdgcn_mfma_f32_16x16x32_bf16(a2, b1, acc1, 0, 0, 0);
        acc2 = __builtin_amdgcn_mfma_f32_16x16x32_bf16(a,  b2, acc2, 0, 0, 0);
        acc2 = __builtin_amdgcn_mfma_f32_16x16x32_bf16(a2, b2, acc2, 0, 0, 0);
        acc3 = __builtin_amdgcn_mfma_f32_16x16x32_bf16(a,  b3, acc3, 0, 0, 0);
        acc3 = __builtin_amdgcn_mfma_f32_16x16x32_bf16(a2, b3, acc3, 0, 0, 0);
        if (t + 1 < NT) {
            *(int4*)(void*)&Ah[(t + 1) & 1][tid << 3] = rh;
            *(int4*)(void*)&Al[(t + 1) & 1][tid << 3] = rl;
            *(int4*)(void*)&Bs[(t + 1) & 1][tid << 3] = rb;
        }
        __syncthreads();
    }

    float* Pp = P + (size_t)blockIdx.z * NGRAPH * N;
    const int rbase = row0 + wave * 16 + ((lane >> 4) << 2);
    const int cbase = col0 + (lane & 15);
#pragma unroll
    for (int r = 0; r < 4; ++r) {
        int grow = rbase + r;
        Pp[(size_t)grow * N + cbase +  0] = acc0[r];
        Pp[(size_t)grow * N + cbase + 16] = acc1[r];
        Pp[(size_t)grow * N + cbase + 32] = acc2[r];
        Pp[(size_t)grow * N + cbase + 48] = acc3[r];
    }
}

// ---------------------------------------------------------------------------
// Fused split-K reduce + bias + BN partial stats (16-row groups).
// grid (N/256, 16).
// ---------------------------------------------------------------------------
__global__ __launch_bounds__(256) void reduce_stats(const float* __restrict__ P,
                                                    const float* __restrict__ bias,
                                                    float* __restrict__ M_,
                                                    float* __restrict__ ps,
                                                    float* __restrict__ pss,
                                                    int N, int S)
{
    int f = blockIdx.x * 256 + threadIdx.x;
    int r0 = blockIdx.y * 16;
    size_t MN = (size_t)NGRAPH * N;
    float bv = bias[f];
    float s = 0.f, ss = 0.f;
    for (int r = r0; r < r0 + 16; ++r) {
        float v = 0.f;
        for (int t = 0; t < S; ++t) v += P[(size_t)t * MN + (size_t)r * N + f];
        v += bv;
        M_[(size_t)r * N + f] = v;
        s += v; ss += v * v;
    }
    ps [(size_t)blockIdx.y * N + f] = s;
    pss[(size_t)blockIdx.y * N + f] = ss;
}

// ---------------------------------------------------------------------------
// BN apply + ReLU -> split-bf16 hi/lo planes.
// ---------------------------------------------------------------------------
__global__ __launch_bounds__(256) void bn_apply_bf(const float* __restrict__ M_,
                                                   const float* __restrict__ mean,
                                                   const float* __restrict__ inv,
                                                   const float* __restrict__ gamma,
                                                   const float* __restrict__ beta,
                                                   unsigned short* __restrict__ hi,
                                                   unsigned short* __restrict__ lo,
                                                   int total, int mask)
{
    int i = blockIdx.x * 256 + threadIdx.x;
    if (i >= total) return;
    int f = i & mask;
    float v = (M_[i] - mean[f]) * inv[f] * gamma[f] + beta[f];
    v = fmaxf(v, 0.f);
    unsigned short h = f2b(v);
    hi[i] = h;
    lo[i] = f2b(v - b2f(h));
}

// ---------------------------------------------------------------------------
// Final tiny linear from hi/lo bf16: out[g][0:2] = m3[g] @ Wm4 + bm4
// ---------------------------------------------------------------------------
__global__ __launch_bounds__(256) void final_kernel(const unsigned short* __restrict__ Xhi,
                                                    const unsigned short* __restrict__ Xlo,
                                                    const float* __restrict__ W,
                                                    const float* __restrict__ b,
                                                    float* __restrict__ out)
{
    int g = blockIdx.x;
    float s0 = 0.f, s1 = 0.f;
    for (int k = threadIdx.x; k < HID2; k += 256) {
        float v = b2f(Xhi[(size_t)g * HID2 + k]) + b2f(Xlo[(size_t)g * HID2 + k]);
        s0 += v * W[k * 2 + 0];
        s1 += v * W[k * 2 + 1];
    }
    __shared__ float r0[256], r1[256];
    r0[threadIdx.x] = s0; r1[threadIdx.x] = s1;
    __syncthreads();
    for (int w = 128; w > 0; w >>= 1) {
        if (threadIdx.x < w) {
            r0[threadIdx.x] += r0[threadIdx.x + w];
            r1[threadIdx.x] += r1[threadIdx.x + w];
        }
        __syncthreads();
    }
    if (threadIdx.x == 0) {
        out[g * 2 + 0] = r0[0] + b[0];
        out[g * 2 + 1] = r1[0] + b[1];
    }
}

// ---------------------------------------------------------------------------
extern "C" void kernel_launch(void* const* d_in, const int* in_sizes, int n_in,
                              void* d_out, int out_size, void* d_ws, size_t ws_size,
                              hipStream_t stream)
{
    const float* x      = (const float*)d_in[0];
    const float* Wg0    = (const float*)d_in[1];
    const float* bg0    = (const float*)d_in[2];
    const float* WgR    = (const float*)d_in[3];
    const float* bgR    = (const float*)d_in[4];
    const float* gx     = (const float*)d_in[5];
    const float* bx     = (const float*)d_in[6];
    const float* gh     = (const float*)d_in[7];
    const float* bh     = (const float*)d_in[8];
    const float* Watt   = (const float*)d_in[9];
    const float* batt   = (const float*)d_in[10];
    const float* Wm1    = (const float*)d_in[11];
    const float* bm1    = (const float*)d_in[12];
    const float* gm1    = (const float*)d_in[13];
    const float* bem1   = (const float*)d_in[14];
    const float* Wm2    = (const float*)d_in[15];
    const float* bm2    = (const float*)d_in[16];
    const float* gm2    = (const float*)d_in[17];
    const float* bem2   = (const float*)d_in[18];
    const float* Wm3    = (const float*)d_in[19];
    const float* bm3    = (const float*)d_in[20];
    const float* gm3    = (const float*)d_in[21];
    const float* bem3   = (const float*)d_in[22];
    const float* Wm4    = (const float*)d_in[23];
    const float* bm4    = (const float*)d_in[24];
    const int*   esrc   = (const int*)d_in[25];
    const int*   edst   = (const int*)d_in[26];
    float* out = (float*)d_out;

    char* w = (char*)d_ws;
    auto alloc = [&](size_t bytes) -> char* {
        char* p = w;
        w += (bytes + 255) & ~(size_t)255;
        return p;
    };
    unsigned short* Wt0   = (unsigned short*)alloc((size_t)512 * 64 * 2);
    unsigned short* Wt123 = (unsigned short*)alloc((size_t)3 * 512 * 512 * 2);
    unsigned short* W1t   = (unsigned short*)alloc((size_t)HID1 * DCAT * 2);
    unsigned short* W2t   = (unsigned short*)alloc((size_t)HID2 * HID1 * 2);
    unsigned short* W3t   = (unsigned short*)alloc((size_t)HID2 * HID2 * 2);
    float*          hs    = (float*)alloc((size_t)NGRAPH * NTRIU * 4);
    float*          xv    = (float*)alloc((size_t)NGRAPH * NTRIU * 4);
    unsigned short* zhi   = (unsigned short*)alloc((size_t)NGRAPH * DCAT * 2);
    unsigned short* zlo   = (unsigned short*)alloc((size_t)NGRAPH * DCAT * 2);
    float*          P     = (float*)alloc((size_t)8 * NGRAPH * HID1 * 4);
    float*          mf    = (float*)alloc((size_t)NGRAPH * HID1 * 4);
    unsigned short* m1hi  = (unsigned short*)alloc((size_t)NGRAPH * HID1 * 2);
    unsigned short* m1lo  = (unsigned short*)alloc((size_t)NGRAPH * HID1 * 2);
    unsigned short* m2hi  = (unsigned short*)alloc((size_t)NGRAPH * HID2 * 2);
    unsigned short* m2lo  = (unsigned short*)alloc((size_t)NGRAPH * HID2 * 2);
    unsigned short* m3hi  = (unsigned short*)alloc((size_t)NGRAPH * HID2 * 2);
    unsigned short* m3lo  = (unsigned short*)alloc((size_t)NGRAPH * HID2 * 2);
    float*          ps    = (float*)alloc((size_t)16 * NTRIU * 4);
    float*          pss   = (float*)alloc((size_t)16 * NTRIU * 4);
    float*          xm    = (float*)alloc(NTRIU * 4);
    float*          xi    = (float*)alloc(NTRIU * 4);
    float*          hm    = (float*)alloc(NTRIU * 4);
    float*          hiv   = (float*)alloc(NTRIU * 4);
    float*          mmean = (float*)alloc(HID1 * 4);
    float*          minv  = (float*)alloc(HID1 * 4);
    int*            off   = (int*)alloc(NTRIU * 4);

    hipFuncSetAttribute((const void*)gcn_all,
                        hipFuncAttributeMaxDynamicSharedMemorySize, GCN_LDS);

    triu_off<<<1, 64, 0, stream>>>(off);
    convWt<<<dim3(16, 2, 1),   dim3(32, 8), 0, stream>>>(Wg0, Wt0, 64, HC, 64, 0, 0);
    convWt<<<dim3(16, 16, 3),  dim3(32, 8), 0, stream>>>(WgR, Wt123, HC, HC, 512,
                                                         (long long)HC * HC, 512LL * 512);
    convWt<<<dim3(32, 126, 1), dim3(32, 8), 0, stream>>>(Wm1, W1t, DCAT, HID1, DCAT, 0, 0);
    convWt<<<dim3(16, 32, 1),  dim3(32, 8), 0, stream>>>(Wm2, W2t, HID1, HID2, HID1, 0, 0);
    convWt<<<dim3(16, 16, 1),  dim3(32, 8), 0, stream>>>(Wm3, W3t, HID2, HID2, HID2, 0, 0);

    // Whole GCN (adjacency build + 4 layers + pool) in one kernel
    gcn_all<<<NGRAPH, 256, GCN_LDS, stream>>>(x, esrc, edst, Wt0, Wt123, bg0, bgR, hs);

    // BN stats for h and xv, fused attention + z (split-bf16)
    stats_part<<<dim3(8, 16), 256, 0, stream>>>(hs, ps, pss, NTRIU, 16);
    stats_fin<<<8, 256, 0, stream>>>(ps, pss, hm, hiv, NTRIU, 16, 1.0f / NGRAPH);
    xv_gather<<<dim3(8, 16), 256, 0, stream>>>(x, off, xv, ps, pss);
    stats_fin<<<8, 256, 0, stream>>>(ps, pss, xm, xi, NTRIU, 16, 1.0f / NGRAPH);
    attz_fused<<<NGRAPH, 256, 0, stream>>>(xv, xm, xi, gx, bx, hs, hm, hiv, gh, bh,
                                           Watt, batt, zhi, zlo);

    // MLP layer 1: [256,4032] @ [4032,1024]
    gemm_bf_sk<<<dim3(16, 4, 7), 256, 0, stream>>>(zhi, zlo, W1t, P, HID1, DCAT, 576);
    reduce_stats<<<dim3(4, 16), 256, 0, stream>>>(P, bm1, mf, ps, pss, HID1, 7);
    stats_fin<<<4, 256, 0, stream>>>(ps, pss, mmean, minv, HID1, 16, 1.0f / NGRAPH);
    bn_apply_bf<<<1024, 256, 0, stream>>>(mf, mmean, minv, gm1, bem1, m1hi, m1lo,
                                          NGRAPH * HID1, HID1 - 1);

    // MLP layer 2: [256,1024] @ [1024,512]
    gemm_bf_sk<<<dim3(8, 4, 8), 256, 0, stream>>>(m1hi, m1lo, W2t, P, HID2, HID1, 128);
    reduce_stats<<<dim3(2, 16), 256, 0, stream>>>(P, bm2, mf, ps, pss, HID2, 8);
    stats_fin<<<2, 256, 0, stream>>>(ps, pss, mmean, minv, HID2, 16, 1.0f / NGRAPH);
    bn_apply_bf<<<512, 256, 0, stream>>>(mf, mmean, minv, gm2, bem2, m2hi, m2lo,
                                         NGRAPH * HID2, HID2 - 1);

    // MLP layer 3: [256,512] @ [512,512]
    gemm_bf_sk<<<dim3(8, 4, 8), 256, 0, stream>>>(m2hi, m2lo, W3t, P, HID2, HID2, 64);
    reduce_stats<<<dim3(2, 16), 256, 0, stream>>>(P, bm3, mf, ps, pss, HID2, 8);
    stats_fin<<<2, 256, 0, stream>>>(ps, pss, mmean, minv, HID2, 16, 1.0f / NGRAPH);
    bn_apply_bf<<<512, 256, 0, stream>>>(mf, mmean, minv, gm3, bem3, m3hi, m3lo,
                                         NGRAPH * HID2, HID2 - 1);

    final_kernel<<<NGRAPH, 256, 0, stream>>>(m3hi, m3lo, Wm4, bm4, out);
}